// Round 2
// baseline (836.349 us; speedup 1.0000x reference)
//
#include <hip/hip_runtime.h>
#include <float.h>
#include <math.h>

#define B_ 32
#define S_ 2048
#define H_ 1024
#define M_ 128
#define N_ 500000
#define KK 16
#define ALPHA_ 0.1f
#define TAU_ 0.1f
#define EPS_ 1e-5f
#define MAX_NORM_ 0.99999f
#define MAXN2_ (MAX_NORM_ * MAX_NORM_)
#define SC_ 16                       // pooling chunks over S
#define CH_ 512                      // memory rows per block in k3
#define NBLK_ ((N_ + CH_ - 1) / CH_) // 977
#define NBLK2_ (2 * NBLK_)           // 1954 virtual half-blocks

// ---------------------------------------------------------------- k1: pool partial sums
__global__ __launch_bounds__(256) void k1_pool(const float* __restrict__ hid,
                                               float* __restrict__ pp) {
    int bid = blockIdx.x;
    int b = bid >> 4, sc = bid & 15;
    const float4* h4 = (const float4*)hid;
    float4 acc = {0.f, 0.f, 0.f, 0.f};
    int s0 = sc * (S_ / SC_);
    for (int s = 0; s < S_ / SC_; ++s) {
        float4 v = h4[((size_t)(b * S_ + s0 + s) << 8) + threadIdx.x];
        acc.x += v.x; acc.y += v.y; acc.z += v.z; acc.w += v.w;
    }
    ((float4*)pp)[(size_t)(b * SC_ + sc) * 256 + threadIdx.x] = acc;
}

// ---------------------------------------------------------------- k2: query network (tiny)
__device__ __forceinline__ float block_reduce_sum_128(float v, volatile float* red, int tid) {
    red[tid] = v;
    __syncthreads();
    if (tid < 64) red[tid] += red[tid + 64];
    __syncthreads();
    if (tid < 64) {
        float x = red[tid];
        #pragma unroll
        for (int off = 32; off >= 1; off >>= 1) x += __shfl_down(x, off);
        if (tid == 0) red[0] = x;
    }
    __syncthreads();
    float r = red[0];
    __syncthreads();
    return r;
}

__global__ void k2_query(const float* __restrict__ pp, const float* __restrict__ W1,
                         const float* __restrict__ b1, const float* __restrict__ ln_g,
                         const float* __restrict__ ln_b, const float* __restrict__ W2,
                         const float* __restrict__ b2, const float* __restrict__ qorig,
                         float* __restrict__ query, float* __restrict__ qstats) {
    __shared__ float pooled[H_];
    __shared__ float red[128];
    __shared__ float hv[M_];
    int b = blockIdx.x, tid = threadIdx.x; // 128 threads
    #pragma unroll
    for (int j = 0; j < H_ / 128; ++j) {
        int h = tid + j * 128;
        float s = 0.f;
        for (int sc = 0; sc < SC_; ++sc) s += pp[(size_t)(b * SC_ + sc) * H_ + h];
        pooled[h] = s * (1.0f / (float)S_);
    }
    __syncthreads();
    int m = tid;
    float x = b1[m];
    for (int k = 0; k < H_; ++k) x = fmaf(pooled[k], W1[k * M_ + m], x);
    // layernorm
    float mu = block_reduce_sum_128(x, red, tid) * (1.0f / (float)M_);
    float dmu = x - mu;
    float var = block_reduce_sum_128(dmu * dmu, red, tid) * (1.0f / (float)M_);
    float xh = dmu * rsqrtf(var + 1e-5f) * ln_g[m] + ln_b[m];
    // exact gelu
    float g = 0.5f * xh * (1.0f + erff(xh * 0.70710678f));
    hv[m] = g;
    __syncthreads();
    float t = b2[m];
    for (int k = 0; k < M_; ++k) t = fmaf(hv[k], W2[k * M_ + m], t);
    // origin = project(q_origin)
    float o = qorig[m];
    float on2 = block_reduce_sum_128(o * o, red, tid);
    float on = fmaxf(sqrtf(on2), EPS_);
    float osc = 1.0f / fmaxf(on / MAX_NORM_, 1.0f);
    float u = o * osc;
    // exp_map second term
    float vn2 = block_reduce_sum_128(t * t, red, tid);
    float vn = fmaxf(sqrtf(vn2), EPS_);
    float sec = tanhf(vn * 0.5f) * t / vn;
    // mobius_add(u, sec)
    float dot_uv = block_reduce_sum_128(u * sec, red, tid);
    float nu = fminf(fmaxf(block_reduce_sum_128(u * u, red, tid), 0.f), MAXN2_);
    float nv = fminf(fmaxf(block_reduce_sum_128(sec * sec, red, tid), 0.f), MAXN2_);
    float num = (1.0f + 2.0f * dot_uv + nv) * u + (1.0f - nu) * sec;
    float den = 1.0f + 2.0f * dot_uv + nu * nv;
    float r = num / fmaxf(den, EPS_);
    // project
    float rn2 = block_reduce_sum_128(r * r, red, tid);
    float rn = fmaxf(sqrtf(rn2), EPS_);
    float rsc = 1.0f / fmaxf(rn / MAX_NORM_, 1.0f);
    float q = r * rsc;
    query[b * M_ + m] = q;
    float qq = block_reduce_sum_128(q * q, red, tid);
    if (tid == 0) {
        qstats[b * 2 + 0] = qq; // raw sum q*q (used in dist_sq)
        float qn = fminf(fmaxf(qq, 0.f), MAXN2_);
        qstats[b * 2 + 1] = 1.0f - qn; // (1 - qn_clipped)
    }
}

// ---------------------------------------------------------------- k3: scores + per-block top-16
__device__ __forceinline__ void block_select16(const float* sc_s, int rows_base, int vblk,
                                               float* __restrict__ cand_val,
                                               int* __restrict__ cand_idx, int tid) {
    int wave = tid >> 6, lane = tid & 63;
    // 4 waves x 8 batches each = all 32 batches
    for (int j = 0; j < 8; ++j) {
        int b = wave * 8 + j;
        float vals[4]; int rows[4];
        #pragma unroll
        for (int i = 0; i < 4; ++i) {
            int rr = lane + i * 64;
            vals[i] = sc_s[rr * 33 + b];
            rows[i] = rr;
        }
        for (int k = 0; k < KK; ++k) {
            float best = vals[0]; int bi = rows[0];
            #pragma unroll
            for (int i = 1; i < 4; ++i)
                if (vals[i] < best) { best = vals[i]; bi = rows[i]; }
            #pragma unroll
            for (int off = 32; off >= 1; off >>= 1) {
                float ov = __shfl_down(best, off);
                int oi = __shfl_down(bi, off);
                if (ov < best) { best = ov; bi = oi; }
            }
            bi = __shfl(bi, 0);
            best = __shfl(best, 0);
            if (lane == 0) {
                cand_val[((size_t)vblk * B_ + b) * KK + k] = best;
                cand_idx[((size_t)vblk * B_ + b) * KK + k] = rows_base + bi;
            }
            #pragma unroll
            for (int i = 0; i < 4; ++i)
                if (rows[i] == bi) vals[i] = FLT_MAX;
        }
    }
}

__global__ __launch_bounds__(256) void k3_scores(const float* __restrict__ mem,
                                                 const float* __restrict__ query,
                                                 const float* __restrict__ qstats,
                                                 float* __restrict__ cand_val,
                                                 int* __restrict__ cand_idx) {
    __shared__ float q_s[B_ * M_];
    __shared__ float qq_s[B_], omq_s[B_];
    __shared__ float sc_s[256 * 33];
    int tid = threadIdx.x, bid = blockIdx.x;
    for (int i = tid; i < B_ * M_; i += 256) q_s[i] = query[i];
    if (tid < B_) { qq_s[tid] = qstats[tid * 2]; omq_s[tid] = qstats[tid * 2 + 1]; }
    __syncthreads();

    int r0 = bid * CH_ + tid;
    int r1 = r0 + 256;
    bool v0 = r0 < N_, v1 = r1 < N_;
    const float4* m0p = (const float4*)(mem + (size_t)(v0 ? r0 : 0) * M_);
    const float4* m1p = (const float4*)(mem + (size_t)(v1 ? r1 : 0) * M_);

    float acc0[B_], acc1[B_];
    #pragma unroll
    for (int b = 0; b < B_; ++b) { acc0[b] = 0.f; acc1[b] = 0.f; }
    float mm0 = 0.f, mm1 = 0.f;

    for (int kt = 0; kt < M_ / 4; ++kt) {
        float4 a = m0p[kt];
        float4 c = m1p[kt];
        mm0 = fmaf(a.x, a.x, fmaf(a.y, a.y, fmaf(a.z, a.z, fmaf(a.w, a.w, mm0))));
        mm1 = fmaf(c.x, c.x, fmaf(c.y, c.y, fmaf(c.z, c.z, fmaf(c.w, c.w, mm1))));
        #pragma unroll
        for (int b = 0; b < B_; ++b) {
            float4 qv = *(const float4*)&q_s[b * M_ + kt * 4]; // wave-uniform broadcast
            acc0[b] = fmaf(qv.x, a.x, fmaf(qv.y, a.y, fmaf(qv.z, a.z, fmaf(qv.w, a.w, acc0[b]))));
            acc1[b] = fmaf(qv.x, c.x, fmaf(qv.y, c.y, fmaf(qv.z, c.z, fmaf(qv.w, c.w, acc1[b]))));
        }
    }

    float mn0 = fminf(mm0, MAXN2_), mn1 = fminf(mm1, MAXN2_);
    // half A: rows [bid*CH, +256)
    #pragma unroll
    for (int b = 0; b < B_; ++b) {
        float ds0 = fmaxf(qq_s[b] + mm0 - 2.0f * acc0[b], 0.f);
        float t0 = ds0 / fmaxf(omq_s[b] * (1.0f - mn0), EPS_);
        sc_s[tid * 33 + b] = v0 ? t0 : FLT_MAX;
    }
    __syncthreads();
    block_select16(sc_s, bid * CH_, 2 * bid, cand_val, cand_idx, tid);
    __syncthreads();
    // half B: rows [bid*CH+256, +256)
    #pragma unroll
    for (int b = 0; b < B_; ++b) {
        float ds1 = fmaxf(qq_s[b] + mm1 - 2.0f * acc1[b], 0.f);
        float t1 = ds1 / fmaxf(omq_s[b] * (1.0f - mn1), EPS_);
        sc_s[tid * 33 + b] = v1 ? t1 : FLT_MAX;
    }
    __syncthreads();
    block_select16(sc_s, bid * CH_ + 256, 2 * bid + 1, cand_val, cand_idx, tid);
}

// ---------------------------------------------------------------- k4: merge per-block candidates
__global__ __launch_bounds__(256) void k4_merge(const float* __restrict__ cand_val,
                                                const int* __restrict__ cand_idx,
                                                int* __restrict__ topk_idx) {
    __shared__ float tv[256 * KK];
    __shared__ int ti[256 * KK];
    __shared__ float mv[64 * KK];
    __shared__ int mi[64 * KK];
    int b = blockIdx.x, tid = threadIdx.x;
    float val[KK]; int idx[KK];
    #pragma unroll
    for (int i = 0; i < KK; ++i) { val[i] = FLT_MAX; idx[i] = 0; }
    int nc = NBLK2_ * KK;
    for (int c = tid; c < nc; c += 256) {
        int g = c >> 4, k = c & 15;
        float v = cand_val[((size_t)g * B_ + b) * KK + k];
        int id = cand_idx[((size_t)g * B_ + b) * KK + k];
        if (v < val[KK - 1]) {
            val[KK - 1] = v; idx[KK - 1] = id;
            #pragma unroll
            for (int j = KK - 1; j > 0; --j) {
                if (val[j] < val[j - 1]) {
                    float tvv = val[j]; val[j] = val[j - 1]; val[j - 1] = tvv;
                    int tii = idx[j]; idx[j] = idx[j - 1]; idx[j - 1] = tii;
                }
            }
        }
    }
    #pragma unroll
    for (int i = 0; i < KK; ++i) { tv[tid * KK + i] = val[i]; ti[tid * KK + i] = idx[i]; }
    __syncthreads();
    if (tid < 64) {
        #pragma unroll
        for (int i = 0; i < KK; ++i) { val[i] = FLT_MAX; idx[i] = 0; }
        for (int t = tid * 4; t < tid * 4 + 4; ++t) {
            for (int i = 0; i < KK; ++i) { // source sorted ascending
                float v = tv[t * KK + i]; int id = ti[t * KK + i];
                if (v >= val[KK - 1]) break;
                val[KK - 1] = v; idx[KK - 1] = id;
                #pragma unroll
                for (int j = KK - 1; j > 0; --j) {
                    if (val[j] < val[j - 1]) {
                        float tvv = val[j]; val[j] = val[j - 1]; val[j - 1] = tvv;
                        int tii = idx[j]; idx[j] = idx[j - 1]; idx[j - 1] = tii;
                    }
                }
            }
        }
        #pragma unroll
        for (int i = 0; i < KK; ++i) { mv[tid * KK + i] = val[i]; mi[tid * KK + i] = idx[i]; }
        int h = 0;
        for (int k = 0; k < KK; ++k) {
            float cv = (h < KK) ? mv[tid * KK + h] : FLT_MAX;
            int ci = (h < KK) ? mi[tid * KK + h] : 0;
            float bestv = cv; int bestl = tid;
            #pragma unroll
            for (int off = 32; off >= 1; off >>= 1) {
                float ov = __shfl_down(bestv, off);
                int ol = __shfl_down(bestl, off);
                if (ov < bestv) { bestv = ov; bestl = ol; }
            }
            bestl = __shfl(bestl, 0);
            if (tid == bestl) {
                topk_idx[b * KK + k] = ci;
                h++;
            }
        }
    }
}

// ---------------------------------------------------------------- k5: exact dists, softmax, retrieve, force
__global__ void k5_retrieve(const float* __restrict__ mem, const float* __restrict__ query,
                            const float* __restrict__ qstats, const int* __restrict__ topk_idx,
                            const float* __restrict__ Wp, const float* __restrict__ bp,
                            float* __restrict__ force) {
    __shared__ float q_s[M_];
    __shared__ float d_s[KK];
    __shared__ float w_s[KK];
    __shared__ int idx_s[KK];
    __shared__ float ret_s[M_];
    int b = blockIdx.x, tid = threadIdx.x; // 256 threads
    if (tid < M_) q_s[tid] = query[b * M_ + tid];
    if (tid < KK) {
        int id = topk_idx[b * KK + tid];
        idx_s[tid] = (id < 0) ? 0 : ((id >= N_) ? (N_ - 1) : id); // defensive clamp
    }
    __syncthreads();
    float qq = qstats[b * 2], omq = qstats[b * 2 + 1];
    int wave = tid >> 6, lane = tid & 63;
    for (int ii = wave; ii < KK; ii += 4) {
        const float* mr = mem + (size_t)idx_s[ii] * M_;
        float a0 = mr[lane], a1 = mr[lane + 64];
        float p = q_s[lane] * a0 + q_s[lane + 64] * a1;
        float mm = a0 * a0 + a1 * a1;
        #pragma unroll
        for (int off = 32; off >= 1; off >>= 1) {
            p += __shfl_down(p, off);
            mm += __shfl_down(mm, off);
        }
        if (lane == 0) {
            float dsq = fmaxf(qq + mm - 2.0f * p, 0.f);
            float mn = fminf(mm, MAXN2_);
            float t = dsq / fmaxf(omq * (1.0f - mn), EPS_);
            d_s[ii] = acoshf(1.0f + 2.0f * t);
        }
    }
    __syncthreads();
    if (tid == 0) {
        float dmin = d_s[0];
        for (int i = 1; i < KK; ++i) dmin = fminf(dmin, d_s[i]);
        float Z = 0.f;
        for (int i = 0; i < KK; ++i) {
            float w = expf((dmin - d_s[i]) * (1.0f / TAU_));
            w_s[i] = w; Z += w;
        }
        float iZ = 1.0f / Z;
        for (int i = 0; i < KK; ++i) w_s[i] *= iZ;
    }
    __syncthreads();
    if (tid < M_) {
        float r = 0.f;
        for (int i = 0; i < KK; ++i) r = fmaf(w_s[i], mem[(size_t)idx_s[i] * M_ + tid], r);
        ret_s[tid] = r;
    }
    __syncthreads();
    #pragma unroll
    for (int j = 0; j < 4; ++j) {
        int h = tid + j * 256;
        float f = bp[h];
        for (int k = 0; k < M_; ++k) f = fmaf(ret_s[k], Wp[k * H_ + h], f);
        force[b * H_ + h] = f;
    }
}

// ---------------------------------------------------------------- k6: out = hidden + alpha*force
__global__ __launch_bounds__(256) void k6_out(const float* __restrict__ hid,
                                              const float* __restrict__ force,
                                              float* __restrict__ out) {
    const float4* h4 = (const float4*)hid;
    const float4* f4 = (const float4*)force;
    float4* o4 = (float4*)out;
    int n4 = B_ * S_ * H_ / 4; // 16,777,216
    for (int i = blockIdx.x * blockDim.x + threadIdx.x; i < n4; i += gridDim.x * blockDim.x) {
        int b = i >> 19; // (S*H/4) = 2^19
        float4 hv = h4[i];
        float4 fv = f4[(b << 8) + (i & 255)];
        float4 ov;
        ov.x = fmaf(ALPHA_, fv.x, hv.x);
        ov.y = fmaf(ALPHA_, fv.y, hv.y);
        ov.z = fmaf(ALPHA_, fv.z, hv.z);
        ov.w = fmaf(ALPHA_, fv.w, hv.w);
        o4[i] = ov;
    }
}

// ---------------------------------------------------------------- launch
extern "C" void kernel_launch(void* const* d_in, const int* in_sizes, int n_in,
                              void* d_out, int out_size, void* d_ws, size_t ws_size,
                              hipStream_t stream) {
    const float* hid    = (const float*)d_in[0];
    const float* W1     = (const float*)d_in[1];
    const float* b1     = (const float*)d_in[2];
    const float* ln_g   = (const float*)d_in[3];
    const float* ln_b   = (const float*)d_in[4];
    const float* W2     = (const float*)d_in[5];
    const float* b2     = (const float*)d_in[6];
    const float* qorig  = (const float*)d_in[7];
    const float* mem    = (const float*)d_in[8];
    const float* Wp     = (const float*)d_in[9];
    const float* bp     = (const float*)d_in[10];
    float* out = (float*)d_out;

    char* ws = (char*)d_ws;
    size_t off = 0;
    float* pp = (float*)(ws + off);       off += (size_t)B_ * SC_ * H_ * 4;
    float* query = (float*)(ws + off);    off += (size_t)B_ * M_ * 4;
    float* qstats = (float*)(ws + off);   off += (size_t)B_ * 2 * 4;
    float* cand_val = (float*)(ws + off); off += (size_t)NBLK2_ * B_ * KK * 4;
    int* cand_idx = (int*)(ws + off);     off += (size_t)NBLK2_ * B_ * KK * 4;
    int* topk_idx = (int*)(ws + off);     off += (size_t)B_ * KK * 4;
    float* force = (float*)(ws + off);    off += (size_t)B_ * H_ * 4;
    (void)ws_size; (void)in_sizes; (void)n_in; (void)out_size;

    hipLaunchKernelGGL(k1_pool, dim3(B_ * SC_), dim3(256), 0, stream, hid, pp);
    hipLaunchKernelGGL(k2_query, dim3(B_), dim3(128), 0, stream, pp, W1, b1, ln_g, ln_b,
                       W2, b2, qorig, query, qstats);
    hipLaunchKernelGGL(k3_scores, dim3(NBLK_), dim3(256), 0, stream, mem, query, qstats,
                       cand_val, cand_idx);
    hipLaunchKernelGGL(k4_merge, dim3(B_), dim3(256), 0, stream, cand_val, cand_idx, topk_idx);
    hipLaunchKernelGGL(k5_retrieve, dim3(B_), dim3(256), 0, stream, mem, query, qstats,
                       topk_idx, Wp, bp, force);
    hipLaunchKernelGGL(k6_out, dim3(2048), dim3(256), 0, stream, hid, force, out);
}

// Round 3
// 657.359 us; speedup vs baseline: 1.2723x; 1.2723x over previous
//
#include <hip/hip_runtime.h>
#include <float.h>
#include <math.h>

#define B_ 32
#define S_ 2048
#define H_ 1024
#define M_ 128
#define N_ 500000
#define KK 16
#define ALPHA_ 0.1f
#define TAU_ 0.1f
#define EPS_ 1e-5f
#define MAX_NORM_ 0.99999f
#define MAXN2_ (MAX_NORM_ * MAX_NORM_)
#define SC_ 16                       // pooling chunks over S
#define CH_ 512                      // memory rows per block in k3
#define NBLK_ ((N_ + CH_ - 1) / CH_) // 977
#define NBLK2_ (2 * NBLK_)           // 1954 virtual half-blocks

// ---------------------------------------------------------------- k1: pool partial sums
__global__ __launch_bounds__(256) void k1_pool(const float* __restrict__ hid,
                                               float* __restrict__ pp) {
    int bid = blockIdx.x;
    int b = bid >> 4, sc = bid & 15;
    const float4* h4 = (const float4*)hid;
    float4 acc = {0.f, 0.f, 0.f, 0.f};
    int s0 = sc * (S_ / SC_);
    for (int s = 0; s < S_ / SC_; ++s) {
        float4 v = h4[((size_t)(b * S_ + s0 + s) << 8) + threadIdx.x];
        acc.x += v.x; acc.y += v.y; acc.z += v.z; acc.w += v.w;
    }
    ((float4*)pp)[(size_t)(b * SC_ + sc) * 256 + threadIdx.x] = acc;
}

// ---------------------------------------------------------------- k2: query network (tiny)
__device__ __forceinline__ float block_reduce_sum_128(float v, volatile float* red, int tid) {
    red[tid] = v;
    __syncthreads();
    if (tid < 64) red[tid] += red[tid + 64];
    __syncthreads();
    if (tid < 64) {
        float x = red[tid];
        #pragma unroll
        for (int off = 32; off >= 1; off >>= 1) x += __shfl_down(x, off);
        if (tid == 0) red[0] = x;
    }
    __syncthreads();
    float r = red[0];
    __syncthreads();
    return r;
}

__global__ void k2_query(const float* __restrict__ pp, const float* __restrict__ W1,
                         const float* __restrict__ b1, const float* __restrict__ ln_g,
                         const float* __restrict__ ln_b, const float* __restrict__ W2,
                         const float* __restrict__ b2, const float* __restrict__ qorig,
                         float* __restrict__ query, float* __restrict__ qstats) {
    __shared__ float pooled[H_];
    __shared__ float red[128];
    __shared__ float hv[M_];
    int b = blockIdx.x, tid = threadIdx.x; // 128 threads
    #pragma unroll
    for (int j = 0; j < H_ / 128; ++j) {
        int h = tid + j * 128;
        float s = 0.f;
        for (int sc = 0; sc < SC_; ++sc) s += pp[(size_t)(b * SC_ + sc) * H_ + h];
        pooled[h] = s * (1.0f / (float)S_);
    }
    __syncthreads();
    int m = tid;
    float x = b1[m];
    for (int k = 0; k < H_; ++k) x = fmaf(pooled[k], W1[k * M_ + m], x);
    // layernorm
    float mu = block_reduce_sum_128(x, red, tid) * (1.0f / (float)M_);
    float dmu = x - mu;
    float var = block_reduce_sum_128(dmu * dmu, red, tid) * (1.0f / (float)M_);
    float xh = dmu * rsqrtf(var + 1e-5f) * ln_g[m] + ln_b[m];
    // exact gelu
    float g = 0.5f * xh * (1.0f + erff(xh * 0.70710678f));
    hv[m] = g;
    __syncthreads();
    float t = b2[m];
    for (int k = 0; k < M_; ++k) t = fmaf(hv[k], W2[k * M_ + m], t);
    // origin = project(q_origin)
    float o = qorig[m];
    float on2 = block_reduce_sum_128(o * o, red, tid);
    float on = fmaxf(sqrtf(on2), EPS_);
    float osc = 1.0f / fmaxf(on / MAX_NORM_, 1.0f);
    float u = o * osc;
    // exp_map second term
    float vn2 = block_reduce_sum_128(t * t, red, tid);
    float vn = fmaxf(sqrtf(vn2), EPS_);
    float sec = tanhf(vn * 0.5f) * t / vn;
    // mobius_add(u, sec)
    float dot_uv = block_reduce_sum_128(u * sec, red, tid);
    float nu = fminf(fmaxf(block_reduce_sum_128(u * u, red, tid), 0.f), MAXN2_);
    float nv = fminf(fmaxf(block_reduce_sum_128(sec * sec, red, tid), 0.f), MAXN2_);
    float num = (1.0f + 2.0f * dot_uv + nv) * u + (1.0f - nu) * sec;
    float den = 1.0f + 2.0f * dot_uv + nu * nv;
    float r = num / fmaxf(den, EPS_);
    // project
    float rn2 = block_reduce_sum_128(r * r, red, tid);
    float rn = fmaxf(sqrtf(rn2), EPS_);
    float rsc = 1.0f / fmaxf(rn / MAX_NORM_, 1.0f);
    float q = r * rsc;
    query[b * M_ + m] = q;
    float qq = block_reduce_sum_128(q * q, red, tid);
    if (tid == 0) {
        qstats[b * 2 + 0] = qq; // raw sum q*q (used in dist_sq)
        float qn = fminf(fmaxf(qq, 0.f), MAXN2_);
        qstats[b * 2 + 1] = 1.0f - qn; // (1 - qn_clipped)
    }
}

// ---------------------------------------------------------------- k3: scores + per-block top-16
__device__ __forceinline__ void block_select16(const float* sc_s, int rows_base, int vblk,
                                               float* __restrict__ cand_val,
                                               int* __restrict__ cand_idx, int tid) {
    int wave = tid >> 6, lane = tid & 63;
    // 4 waves x 8 batches each = all 32 batches
    for (int j = 0; j < 8; ++j) {
        int b = wave * 8 + j;
        float vals[4]; int rows[4];
        #pragma unroll
        for (int i = 0; i < 4; ++i) {
            int rr = lane + i * 64;
            vals[i] = sc_s[rr * 33 + b];
            rows[i] = rr;
        }
        for (int k = 0; k < KK; ++k) {
            float best = vals[0]; int bi = rows[0];
            #pragma unroll
            for (int i = 1; i < 4; ++i)
                if (vals[i] < best) { best = vals[i]; bi = rows[i]; }
            #pragma unroll
            for (int off = 32; off >= 1; off >>= 1) {
                float ov = __shfl_down(best, off);
                int oi = __shfl_down(bi, off);
                if (ov < best) { best = ov; bi = oi; }
            }
            bi = __shfl(bi, 0);
            best = __shfl(best, 0);
            if (lane == 0) {
                cand_val[((size_t)vblk * B_ + b) * KK + k] = best;
                cand_idx[((size_t)vblk * B_ + b) * KK + k] = rows_base + bi;
            }
            #pragma unroll
            for (int i = 0; i < 4; ++i)
                if (rows[i] == bi) vals[i] = FLT_MAX;
        }
    }
}

__global__ __launch_bounds__(256) void k3_scores(const float* __restrict__ mem,
                                                 const float* __restrict__ query,
                                                 const float* __restrict__ qstats,
                                                 float* __restrict__ cand_val,
                                                 int* __restrict__ cand_idx) {
    __shared__ float q_s[B_ * M_];
    __shared__ float qq_s[B_], omq_s[B_];
    __shared__ float sc_s[256 * 33];
    int tid = threadIdx.x, bid = blockIdx.x;
    for (int i = tid; i < B_ * M_; i += 256) q_s[i] = query[i];
    if (tid < B_) { qq_s[tid] = qstats[tid * 2]; omq_s[tid] = qstats[tid * 2 + 1]; }
    __syncthreads();

    int r0 = bid * CH_ + tid;
    int r1 = r0 + 256;
    bool v0 = r0 < N_, v1 = r1 < N_;
    const float4* m0p = (const float4*)(mem + (size_t)(v0 ? r0 : 0) * M_);
    const float4* m1p = (const float4*)(mem + (size_t)(v1 ? r1 : 0) * M_);

    float acc0[B_], acc1[B_];
    #pragma unroll
    for (int b = 0; b < B_; ++b) { acc0[b] = 0.f; acc1[b] = 0.f; }
    float mm0 = 0.f, mm1 = 0.f;

    // 8 chunks of one 64B cacheline per row: 4x float4 loads issued
    // back-to-back per row so each line is fetched once (L1/MSHR coalesce),
    // 8-16 loads in flight per wave.
    #pragma unroll 2
    for (int ko = 0; ko < 8; ++ko) {
        float4 a[4], c[4];
        #pragma unroll
        for (int i = 0; i < 4; ++i) { a[i] = m0p[ko * 4 + i]; }
        #pragma unroll
        for (int i = 0; i < 4; ++i) { c[i] = m1p[ko * 4 + i]; }
        #pragma unroll
        for (int i = 0; i < 4; ++i) {
            mm0 = fmaf(a[i].x, a[i].x, fmaf(a[i].y, a[i].y, fmaf(a[i].z, a[i].z, fmaf(a[i].w, a[i].w, mm0))));
            mm1 = fmaf(c[i].x, c[i].x, fmaf(c[i].y, c[i].y, fmaf(c[i].z, c[i].z, fmaf(c[i].w, c[i].w, mm1))));
        }
        #pragma unroll
        for (int b = 0; b < B_; ++b) {
            const float4* qb = (const float4*)&q_s[b * M_ + ko * 16];
            #pragma unroll
            for (int i = 0; i < 4; ++i) {
                float4 qv = qb[i]; // wave-uniform broadcast, conflict-free
                acc0[b] = fmaf(qv.x, a[i].x, fmaf(qv.y, a[i].y, fmaf(qv.z, a[i].z, fmaf(qv.w, a[i].w, acc0[b]))));
                acc1[b] = fmaf(qv.x, c[i].x, fmaf(qv.y, c[i].y, fmaf(qv.z, c[i].z, fmaf(qv.w, c[i].w, acc1[b]))));
            }
        }
    }

    float mn0 = fminf(mm0, MAXN2_), mn1 = fminf(mm1, MAXN2_);
    // half A: rows [bid*CH, +256)
    #pragma unroll
    for (int b = 0; b < B_; ++b) {
        float ds0 = fmaxf(qq_s[b] + mm0 - 2.0f * acc0[b], 0.f);
        float t0 = ds0 / fmaxf(omq_s[b] * (1.0f - mn0), EPS_);
        sc_s[tid * 33 + b] = v0 ? t0 : FLT_MAX;
    }
    __syncthreads();
    block_select16(sc_s, bid * CH_, 2 * bid, cand_val, cand_idx, tid);
    __syncthreads();
    // half B: rows [bid*CH+256, +256)
    #pragma unroll
    for (int b = 0; b < B_; ++b) {
        float ds1 = fmaxf(qq_s[b] + mm1 - 2.0f * acc1[b], 0.f);
        float t1 = ds1 / fmaxf(omq_s[b] * (1.0f - mn1), EPS_);
        sc_s[tid * 33 + b] = v1 ? t1 : FLT_MAX;
    }
    __syncthreads();
    block_select16(sc_s, bid * CH_ + 256, 2 * bid + 1, cand_val, cand_idx, tid);
}

// ---------------------------------------------------------------- k4: merge per-block candidates
__global__ __launch_bounds__(256) void k4_merge(const float* __restrict__ cand_val,
                                                const int* __restrict__ cand_idx,
                                                int* __restrict__ topk_idx) {
    __shared__ float tv[256 * KK];
    __shared__ int ti[256 * KK];
    __shared__ float mv[64 * KK];
    __shared__ int mi[64 * KK];
    int b = blockIdx.x, tid = threadIdx.x;
    float val[KK]; int idx[KK];
    #pragma unroll
    for (int i = 0; i < KK; ++i) { val[i] = FLT_MAX; idx[i] = 0; }
    int nc = NBLK2_ * KK;
    for (int c = tid; c < nc; c += 256) {
        int g = c >> 4, k = c & 15;
        float v = cand_val[((size_t)g * B_ + b) * KK + k];
        int id = cand_idx[((size_t)g * B_ + b) * KK + k];
        if (v < val[KK - 1]) {
            val[KK - 1] = v; idx[KK - 1] = id;
            #pragma unroll
            for (int j = KK - 1; j > 0; --j) {
                if (val[j] < val[j - 1]) {
                    float tvv = val[j]; val[j] = val[j - 1]; val[j - 1] = tvv;
                    int tii = idx[j]; idx[j] = idx[j - 1]; idx[j - 1] = tii;
                }
            }
        }
    }
    #pragma unroll
    for (int i = 0; i < KK; ++i) { tv[tid * KK + i] = val[i]; ti[tid * KK + i] = idx[i]; }
    __syncthreads();
    if (tid < 64) {
        #pragma unroll
        for (int i = 0; i < KK; ++i) { val[i] = FLT_MAX; idx[i] = 0; }
        for (int t = tid * 4; t < tid * 4 + 4; ++t) {
            for (int i = 0; i < KK; ++i) { // source sorted ascending
                float v = tv[t * KK + i]; int id = ti[t * KK + i];
                if (v >= val[KK - 1]) break;
                val[KK - 1] = v; idx[KK - 1] = id;
                #pragma unroll
                for (int j = KK - 1; j > 0; --j) {
                    if (val[j] < val[j - 1]) {
                        float tvv = val[j]; val[j] = val[j - 1]; val[j - 1] = tvv;
                        int tii = idx[j]; idx[j] = idx[j - 1]; idx[j - 1] = tii;
                    }
                }
            }
        }
        #pragma unroll
        for (int i = 0; i < KK; ++i) { mv[tid * KK + i] = val[i]; mi[tid * KK + i] = idx[i]; }
        int h = 0;
        for (int k = 0; k < KK; ++k) {
            float cv = (h < KK) ? mv[tid * KK + h] : FLT_MAX;
            int ci = (h < KK) ? mi[tid * KK + h] : 0;
            float bestv = cv; int bestl = tid;
            #pragma unroll
            for (int off = 32; off >= 1; off >>= 1) {
                float ov = __shfl_down(bestv, off);
                int ol = __shfl_down(bestl, off);
                if (ov < bestv) { bestv = ov; bestl = ol; }
            }
            bestl = __shfl(bestl, 0);
            if (tid == bestl) {
                topk_idx[b * KK + k] = ci;
                h++;
            }
        }
    }
}

// ---------------------------------------------------------------- k5: exact dists, softmax, retrieve, force
__global__ void k5_retrieve(const float* __restrict__ mem, const float* __restrict__ query,
                            const float* __restrict__ qstats, const int* __restrict__ topk_idx,
                            const float* __restrict__ Wp, const float* __restrict__ bp,
                            float* __restrict__ force) {
    __shared__ float q_s[M_];
    __shared__ float d_s[KK];
    __shared__ float w_s[KK];
    __shared__ int idx_s[KK];
    __shared__ float ret_s[M_];
    int b = blockIdx.x, tid = threadIdx.x; // 256 threads
    if (tid < M_) q_s[tid] = query[b * M_ + tid];
    if (tid < KK) {
        int id = topk_idx[b * KK + tid];
        idx_s[tid] = (id < 0) ? 0 : ((id >= N_) ? (N_ - 1) : id); // defensive clamp
    }
    __syncthreads();
    float qq = qstats[b * 2], omq = qstats[b * 2 + 1];
    int wave = tid >> 6, lane = tid & 63;
    for (int ii = wave; ii < KK; ii += 4) {
        const float* mr = mem + (size_t)idx_s[ii] * M_;
        float a0 = mr[lane], a1 = mr[lane + 64];
        float p = q_s[lane] * a0 + q_s[lane + 64] * a1;
        float mm = a0 * a0 + a1 * a1;
        #pragma unroll
        for (int off = 32; off >= 1; off >>= 1) {
            p += __shfl_down(p, off);
            mm += __shfl_down(mm, off);
        }
        if (lane == 0) {
            float dsq = fmaxf(qq + mm - 2.0f * p, 0.f);
            float mn = fminf(mm, MAXN2_);
            float t = dsq / fmaxf(omq * (1.0f - mn), EPS_);
            d_s[ii] = acoshf(1.0f + 2.0f * t);
        }
    }
    __syncthreads();
    if (tid == 0) {
        float dmin = d_s[0];
        for (int i = 1; i < KK; ++i) dmin = fminf(dmin, d_s[i]);
        float Z = 0.f;
        for (int i = 0; i < KK; ++i) {
            float w = expf((dmin - d_s[i]) * (1.0f / TAU_));
            w_s[i] = w; Z += w;
        }
        float iZ = 1.0f / Z;
        for (int i = 0; i < KK; ++i) w_s[i] *= iZ;
    }
    __syncthreads();
    if (tid < M_) {
        float r = 0.f;
        for (int i = 0; i < KK; ++i) r = fmaf(w_s[i], mem[(size_t)idx_s[i] * M_ + tid], r);
        ret_s[tid] = r;
    }
    __syncthreads();
    #pragma unroll
    for (int j = 0; j < 4; ++j) {
        int h = tid + j * 256;
        float f = bp[h];
        for (int k = 0; k < M_; ++k) f = fmaf(ret_s[k], Wp[k * H_ + h], f);
        force[b * H_ + h] = f;
    }
}

// ---------------------------------------------------------------- k6: out = hidden + alpha*force
__global__ __launch_bounds__(256) void k6_out(const float* __restrict__ hid,
                                              const float* __restrict__ force,
                                              float* __restrict__ out) {
    const float4* h4 = (const float4*)hid;
    const float4* f4 = (const float4*)force;
    float4* o4 = (float4*)out;
    int n4 = B_ * S_ * H_ / 4; // 16,777,216
    for (int i = blockIdx.x * blockDim.x + threadIdx.x; i < n4; i += gridDim.x * blockDim.x) {
        int b = i >> 19; // (S*H/4) = 2^19
        float4 hv = h4[i];
        float4 fv = f4[(b << 8) + (i & 255)];
        float4 ov;
        ov.x = fmaf(ALPHA_, fv.x, hv.x);
        ov.y = fmaf(ALPHA_, fv.y, hv.y);
        ov.z = fmaf(ALPHA_, fv.z, hv.z);
        ov.w = fmaf(ALPHA_, fv.w, hv.w);
        o4[i] = ov;
    }
}

// ---------------------------------------------------------------- launch
extern "C" void kernel_launch(void* const* d_in, const int* in_sizes, int n_in,
                              void* d_out, int out_size, void* d_ws, size_t ws_size,
                              hipStream_t stream) {
    const float* hid    = (const float*)d_in[0];
    const float* W1     = (const float*)d_in[1];
    const float* b1     = (const float*)d_in[2];
    const float* ln_g   = (const float*)d_in[3];
    const float* ln_b   = (const float*)d_in[4];
    const float* W2     = (const float*)d_in[5];
    const float* b2     = (const float*)d_in[6];
    const float* qorig  = (const float*)d_in[7];
    const float* mem    = (const float*)d_in[8];
    const float* Wp     = (const float*)d_in[9];
    const float* bp     = (const float*)d_in[10];
    float* out = (float*)d_out;

    char* ws = (char*)d_ws;
    size_t off = 0;
    float* pp = (float*)(ws + off);       off += (size_t)B_ * SC_ * H_ * 4;
    float* query = (float*)(ws + off);    off += (size_t)B_ * M_ * 4;
    float* qstats = (float*)(ws + off);   off += (size_t)B_ * 2 * 4;
    float* cand_val = (float*)(ws + off); off += (size_t)NBLK2_ * B_ * KK * 4;
    int* cand_idx = (int*)(ws + off);     off += (size_t)NBLK2_ * B_ * KK * 4;
    int* topk_idx = (int*)(ws + off);     off += (size_t)B_ * KK * 4;
    float* force = (float*)(ws + off);    off += (size_t)B_ * H_ * 4;
    (void)ws_size; (void)in_sizes; (void)n_in; (void)out_size;

    hipLaunchKernelGGL(k1_pool, dim3(B_ * SC_), dim3(256), 0, stream, hid, pp);
    hipLaunchKernelGGL(k2_query, dim3(B_), dim3(128), 0, stream, pp, W1, b1, ln_g, ln_b,
                       W2, b2, qorig, query, qstats);
    hipLaunchKernelGGL(k3_scores, dim3(NBLK_), dim3(256), 0, stream, mem, query, qstats,
                       cand_val, cand_idx);
    hipLaunchKernelGGL(k4_merge, dim3(B_), dim3(256), 0, stream, cand_val, cand_idx, topk_idx);
    hipLaunchKernelGGL(k5_retrieve, dim3(B_), dim3(256), 0, stream, mem, query, qstats,
                       topk_idx, Wp, bp, force);
    hipLaunchKernelGGL(k6_out, dim3(2048), dim3(256), 0, stream, hid, force, out);
}

// Round 4
// 441.165 us; speedup vs baseline: 1.8958x; 1.4901x over previous
//
#include <hip/hip_runtime.h>
#include <float.h>
#include <math.h>

#define B_ 32
#define S_ 2048
#define H_ 1024
#define M_ 128
#define N_ 500000
#define KK 16
#define ALPHA_ 0.1f
#define TAU_ 0.1f
#define EPS_ 1e-5f
#define MAX_NORM_ 0.99999f
#define MAXN2_ (MAX_NORM_ * MAX_NORM_)
#define SC_ 64                       // pooling chunks over S
#define CH_ 512                      // memory rows per block in k3
#define NBLK_ ((N_ + CH_ - 1) / CH_) // 977
#define WIN_ 2048                    // selection window rows
#define NWIN_ ((N_ + WIN_ - 1) / WIN_) // 245
#define NPAD_ (NWIN_ * WIN_)         // 501760 padded plane stride

// ---------------------------------------------------------------- k1: pool partial sums
__global__ __launch_bounds__(256) void k1_pool(const float* __restrict__ hid,
                                               float* __restrict__ pp) {
    int bid = blockIdx.x;
    int b = bid >> 6, sc = bid & 63;
    const float4* h4 = (const float4*)hid;
    float4 acc = {0.f, 0.f, 0.f, 0.f};
    int s0 = sc * (S_ / SC_);
    for (int s = 0; s < S_ / SC_; ++s) {
        float4 v = h4[((size_t)(b * S_ + s0 + s) << 8) + threadIdx.x];
        acc.x += v.x; acc.y += v.y; acc.z += v.z; acc.w += v.w;
    }
    ((float4*)pp)[(size_t)(b * SC_ + sc) * 256 + threadIdx.x] = acc;
}

// ---------------------------------------------------------------- k2: query network (tiny)
__device__ __forceinline__ float block_reduce_sum_128(float v, volatile float* red, int tid) {
    red[tid] = v;
    __syncthreads();
    if (tid < 64) red[tid] += red[tid + 64];
    __syncthreads();
    if (tid < 64) {
        float x = red[tid];
        #pragma unroll
        for (int off = 32; off >= 1; off >>= 1) x += __shfl_down(x, off);
        if (tid == 0) red[0] = x;
    }
    __syncthreads();
    float r = red[0];
    __syncthreads();
    return r;
}

__global__ void k2_query(const float* __restrict__ pp, const float* __restrict__ W1,
                         const float* __restrict__ b1, const float* __restrict__ ln_g,
                         const float* __restrict__ ln_b, const float* __restrict__ W2,
                         const float* __restrict__ b2, const float* __restrict__ qorig,
                         float* __restrict__ query, float* __restrict__ qstats) {
    __shared__ float pooled[H_];
    __shared__ float red[128];
    __shared__ float hv[M_];
    int b = blockIdx.x, tid = threadIdx.x; // 128 threads
    #pragma unroll
    for (int j = 0; j < H_ / 128; ++j) {
        int h = tid + j * 128;
        float s = 0.f;
        for (int sc = 0; sc < SC_; ++sc) s += pp[(size_t)(b * SC_ + sc) * H_ + h];
        pooled[h] = s * (1.0f / (float)S_);
    }
    __syncthreads();
    int m = tid;
    float x = b1[m];
    for (int k = 0; k < H_; ++k) x = fmaf(pooled[k], W1[k * M_ + m], x);
    // layernorm
    float mu = block_reduce_sum_128(x, red, tid) * (1.0f / (float)M_);
    float dmu = x - mu;
    float var = block_reduce_sum_128(dmu * dmu, red, tid) * (1.0f / (float)M_);
    float xh = dmu * rsqrtf(var + 1e-5f) * ln_g[m] + ln_b[m];
    // exact gelu
    float g = 0.5f * xh * (1.0f + erff(xh * 0.70710678f));
    hv[m] = g;
    __syncthreads();
    float t = b2[m];
    for (int k = 0; k < M_; ++k) t = fmaf(hv[k], W2[k * M_ + m], t);
    // origin = project(q_origin)
    float o = qorig[m];
    float on2 = block_reduce_sum_128(o * o, red, tid);
    float on = fmaxf(sqrtf(on2), EPS_);
    float osc = 1.0f / fmaxf(on / MAX_NORM_, 1.0f);
    float u = o * osc;
    // exp_map second term
    float vn2 = block_reduce_sum_128(t * t, red, tid);
    float vn = fmaxf(sqrtf(vn2), EPS_);
    float sec = tanhf(vn * 0.5f) * t / vn;
    // mobius_add(u, sec)
    float dot_uv = block_reduce_sum_128(u * sec, red, tid);
    float nu = fminf(fmaxf(block_reduce_sum_128(u * u, red, tid), 0.f), MAXN2_);
    float nv = fminf(fmaxf(block_reduce_sum_128(sec * sec, red, tid), 0.f), MAXN2_);
    float num = (1.0f + 2.0f * dot_uv + nv) * u + (1.0f - nu) * sec;
    float den = 1.0f + 2.0f * dot_uv + nu * nv;
    float r = num / fmaxf(den, EPS_);
    // project
    float rn2 = block_reduce_sum_128(r * r, red, tid);
    float rn = fmaxf(sqrtf(rn2), EPS_);
    float rsc = 1.0f / fmaxf(rn / MAX_NORM_, 1.0f);
    float q = r * rsc;
    query[b * M_ + m] = q;
    float qq = block_reduce_sum_128(q * q, red, tid);
    if (tid == 0) {
        qstats[b * 2 + 0] = qq; // raw sum q*q (used in dist_sq)
        float qn = fminf(fmaxf(qq, 0.f), MAXN2_);
        qstats[b * 2 + 1] = 1.0f - qn; // (1 - qn_clipped)
    }
}

// ---------------------------------------------------------------- k3: pure streaming scorer
// No LDS. q/qstats read with wave-uniform indices -> scalar loads (SGPR),
// vector pipe does only row loads + FMA. Writes fp32 score planes [b][row].
__global__ __launch_bounds__(256) void k3_scores(const float* __restrict__ mem,
                                                 const float* __restrict__ query,
                                                 const float* __restrict__ qstats,
                                                 float* __restrict__ score) {
    int tid = threadIdx.x, bid = blockIdx.x;
    int r0 = bid * CH_ + tid;
    int r1 = r0 + 256;
    bool v0 = r0 < N_, v1 = r1 < N_;
    const float4* m0p = (const float4*)(mem + (size_t)(v0 ? r0 : 0) * M_);
    const float4* m1p = (const float4*)(mem + (size_t)(v1 ? r1 : 0) * M_);
    const float4* q4 = (const float4*)query;

    float acc0[B_], acc1[B_];
    #pragma unroll
    for (int b = 0; b < B_; ++b) { acc0[b] = 0.f; acc1[b] = 0.f; }
    float mm0 = 0.f, mm1 = 0.f;

    #pragma unroll 2
    for (int ko = 0; ko < 8; ++ko) {
        float4 a[4], c[4];
        #pragma unroll
        for (int i = 0; i < 4; ++i) { a[i] = m0p[ko * 4 + i]; }
        #pragma unroll
        for (int i = 0; i < 4; ++i) { c[i] = m1p[ko * 4 + i]; }
        #pragma unroll
        for (int i = 0; i < 4; ++i) {
            mm0 = fmaf(a[i].x, a[i].x, fmaf(a[i].y, a[i].y, fmaf(a[i].z, a[i].z, fmaf(a[i].w, a[i].w, mm0))));
            mm1 = fmaf(c[i].x, c[i].x, fmaf(c[i].y, c[i].y, fmaf(c[i].z, c[i].z, fmaf(c[i].w, c[i].w, mm1))));
        }
        #pragma unroll
        for (int b = 0; b < B_; ++b) {
            #pragma unroll
            for (int i = 0; i < 4; ++i) {
                float4 qv = q4[b * 32 + ko * 4 + i]; // wave-uniform -> s_load
                acc0[b] = fmaf(qv.x, a[i].x, fmaf(qv.y, a[i].y, fmaf(qv.z, a[i].z, fmaf(qv.w, a[i].w, acc0[b]))));
                acc1[b] = fmaf(qv.x, c[i].x, fmaf(qv.y, c[i].y, fmaf(qv.z, c[i].z, fmaf(qv.w, c[i].w, acc1[b]))));
            }
        }
    }

    float mn0 = fminf(mm0, MAXN2_), mn1 = fminf(mm1, MAXN2_);
    #pragma unroll
    for (int b = 0; b < B_; ++b) {
        float qq = qstats[b * 2];      // uniform -> scalar load
        float omq = qstats[b * 2 + 1];
        float ds0 = fmaxf(qq + mm0 - 2.0f * acc0[b], 0.f);
        float t0 = ds0 / fmaxf(omq * (1.0f - mn0), EPS_);
        float ds1 = fmaxf(qq + mm1 - 2.0f * acc1[b], 0.f);
        float t1 = ds1 / fmaxf(omq * (1.0f - mn1), EPS_);
        if (v0) score[(size_t)b * NPAD_ + r0] = t0;
        if (v1) score[(size_t)b * NPAD_ + r1] = t1;
    }
}

// ---------------------------------------------------------------- k4a: per-window top-16
// One block per 2048-row window. Each wave handles 8 batches alone: 32 keys/lane
// in registers, 16 extractions of wave-min over packed (quantized score | row).
__global__ __launch_bounds__(256) void k4_sel(const float* __restrict__ score,
                                              float* __restrict__ cand_val,
                                              int* __restrict__ cand_idx) {
    int win = blockIdx.x; // 0..NWIN_-1
    int wave = threadIdx.x >> 6, lane = threadIdx.x & 63;
    int base = win * WIN_;
    #pragma unroll 2
    for (int j = 0; j < 8; ++j) {
        int b = wave * 8 + j;
        const float* sp = score + (size_t)b * NPAD_ + base;
        unsigned keys[32];
        #pragma unroll
        for (int i = 0; i < 32; ++i) {
            int lr = lane + i * 64;
            float v = sp[lr];
            unsigned kb = __float_as_uint(v); // v >= 0 -> bits monotone
            keys[i] = ((base + lr) < N_) ? ((kb & ~2047u) | (unsigned)lr) : 0xFFFFFFFFu;
        }
        for (int k = 0; k < KK; ++k) {
            unsigned m = keys[0];
            #pragma unroll
            for (int i = 1; i < 32; ++i) m = min(m, keys[i]);
            #pragma unroll
            for (int off = 32; off >= 1; off >>= 1)
                m = min(m, (unsigned)__shfl_xor((int)m, off));
            if (lane == 0) {
                cand_val[((size_t)win * B_ + b) * KK + k] = __uint_as_float(m & ~2047u);
                cand_idx[((size_t)win * B_ + b) * KK + k] = base + (int)(m & 2047u);
            }
            #pragma unroll
            for (int i = 0; i < 32; ++i)
                if (keys[i] == m) keys[i] = 0xFFFFFFFFu;
        }
    }
}

// ---------------------------------------------------------------- k4b: merge per-window candidates
__global__ __launch_bounds__(256) void k4_merge(const float* __restrict__ cand_val,
                                                const int* __restrict__ cand_idx,
                                                int* __restrict__ topk_idx) {
    __shared__ float tv[256 * KK];
    __shared__ int ti[256 * KK];
    __shared__ float mv[64 * KK];
    __shared__ int mi[64 * KK];
    int b = blockIdx.x, tid = threadIdx.x;
    float val[KK]; int idx[KK];
    #pragma unroll
    for (int i = 0; i < KK; ++i) { val[i] = FLT_MAX; idx[i] = 0; }
    int nc = NWIN_ * KK; // 3920
    for (int c = tid; c < nc; c += 256) {
        int g = c >> 4, k = c & 15;
        float v = cand_val[((size_t)g * B_ + b) * KK + k];
        int id = cand_idx[((size_t)g * B_ + b) * KK + k];
        if (v < val[KK - 1]) {
            val[KK - 1] = v; idx[KK - 1] = id;
            #pragma unroll
            for (int j = KK - 1; j > 0; --j) {
                if (val[j] < val[j - 1]) {
                    float tvv = val[j]; val[j] = val[j - 1]; val[j - 1] = tvv;
                    int tii = idx[j]; idx[j] = idx[j - 1]; idx[j - 1] = tii;
                }
            }
        }
    }
    #pragma unroll
    for (int i = 0; i < KK; ++i) { tv[tid * KK + i] = val[i]; ti[tid * KK + i] = idx[i]; }
    __syncthreads();
    if (tid < 64) {
        #pragma unroll
        for (int i = 0; i < KK; ++i) { val[i] = FLT_MAX; idx[i] = 0; }
        for (int t = tid * 4; t < tid * 4 + 4; ++t) {
            for (int i = 0; i < KK; ++i) { // source sorted ascending
                float v = tv[t * KK + i]; int id = ti[t * KK + i];
                if (v >= val[KK - 1]) break;
                val[KK - 1] = v; idx[KK - 1] = id;
                #pragma unroll
                for (int j = KK - 1; j > 0; --j) {
                    if (val[j] < val[j - 1]) {
                        float tvv = val[j]; val[j] = val[j - 1]; val[j - 1] = tvv;
                        int tii = idx[j]; idx[j] = idx[j - 1]; idx[j - 1] = tii;
                    }
                }
            }
        }
        #pragma unroll
        for (int i = 0; i < KK; ++i) { mv[tid * KK + i] = val[i]; mi[tid * KK + i] = idx[i]; }
        int h = 0;
        for (int k = 0; k < KK; ++k) {
            float cv = (h < KK) ? mv[tid * KK + h] : FLT_MAX;
            int ci = (h < KK) ? mi[tid * KK + h] : 0;
            float bestv = cv; int bestl = tid;
            #pragma unroll
            for (int off = 32; off >= 1; off >>= 1) {
                float ov = __shfl_down(bestv, off);
                int ol = __shfl_down(bestl, off);
                if (ov < bestv) { bestv = ov; bestl = ol; }
            }
            bestl = __shfl(bestl, 0);
            if (tid == bestl) {
                topk_idx[b * KK + k] = ci;
                h++;
            }
        }
    }
}

// ---------------------------------------------------------------- k5: exact dists, softmax, retrieve, force
__global__ void k5_retrieve(const float* __restrict__ mem, const float* __restrict__ query,
                            const float* __restrict__ qstats, const int* __restrict__ topk_idx,
                            const float* __restrict__ Wp, const float* __restrict__ bp,
                            float* __restrict__ force) {
    __shared__ float q_s[M_];
    __shared__ float d_s[KK];
    __shared__ float w_s[KK];
    __shared__ int idx_s[KK];
    __shared__ float ret_s[M_];
    int b = blockIdx.x, tid = threadIdx.x; // 256 threads
    if (tid < M_) q_s[tid] = query[b * M_ + tid];
    if (tid < KK) {
        int id = topk_idx[b * KK + tid];
        idx_s[tid] = (id < 0) ? 0 : ((id >= N_) ? (N_ - 1) : id); // defensive clamp
    }
    __syncthreads();
    float qq = qstats[b * 2], omq = qstats[b * 2 + 1];
    int wave = tid >> 6, lane = tid & 63;
    for (int ii = wave; ii < KK; ii += 4) {
        const float* mr = mem + (size_t)idx_s[ii] * M_;
        float a0 = mr[lane], a1 = mr[lane + 64];
        float p = q_s[lane] * a0 + q_s[lane + 64] * a1;
        float mm = a0 * a0 + a1 * a1;
        #pragma unroll
        for (int off = 32; off >= 1; off >>= 1) {
            p += __shfl_down(p, off);
            mm += __shfl_down(mm, off);
        }
        if (lane == 0) {
            float dsq = fmaxf(qq + mm - 2.0f * p, 0.f);
            float mn = fminf(mm, MAXN2_);
            float t = dsq / fmaxf(omq * (1.0f - mn), EPS_);
            d_s[ii] = acoshf(1.0f + 2.0f * t);
        }
    }
    __syncthreads();
    if (tid == 0) {
        float dmin = d_s[0];
        for (int i = 1; i < KK; ++i) dmin = fminf(dmin, d_s[i]);
        float Z = 0.f;
        for (int i = 0; i < KK; ++i) {
            float w = expf((dmin - d_s[i]) * (1.0f / TAU_));
            w_s[i] = w; Z += w;
        }
        float iZ = 1.0f / Z;
        for (int i = 0; i < KK; ++i) w_s[i] *= iZ;
    }
    __syncthreads();
    if (tid < M_) {
        float r = 0.f;
        for (int i = 0; i < KK; ++i) r = fmaf(w_s[i], mem[(size_t)idx_s[i] * M_ + tid], r);
        ret_s[tid] = r;
    }
    __syncthreads();
    #pragma unroll
    for (int j = 0; j < 4; ++j) {
        int h = tid + j * 256;
        float f = bp[h];
        for (int k = 0; k < M_; ++k) f = fmaf(ret_s[k], Wp[k * H_ + h], f);
        force[b * H_ + h] = f;
    }
}

// ---------------------------------------------------------------- k6: out = hidden + alpha*force
__global__ __launch_bounds__(256) void k6_out(const float* __restrict__ hid,
                                              const float* __restrict__ force,
                                              float* __restrict__ out) {
    const float4* h4 = (const float4*)hid;
    const float4* f4 = (const float4*)force;
    float4* o4 = (float4*)out;
    int n4 = B_ * S_ * H_ / 4; // 16,777,216
    for (int i = blockIdx.x * blockDim.x + threadIdx.x; i < n4; i += gridDim.x * blockDim.x) {
        int b = i >> 19; // (S*H/4) = 2^19
        float4 hv = h4[i];
        float4 fv = f4[(b << 8) + (i & 255)];
        float4 ov;
        ov.x = fmaf(ALPHA_, fv.x, hv.x);
        ov.y = fmaf(ALPHA_, fv.y, hv.y);
        ov.z = fmaf(ALPHA_, fv.z, hv.z);
        ov.w = fmaf(ALPHA_, fv.w, hv.w);
        o4[i] = ov;
    }
}

// ---------------------------------------------------------------- launch
extern "C" void kernel_launch(void* const* d_in, const int* in_sizes, int n_in,
                              void* d_out, int out_size, void* d_ws, size_t ws_size,
                              hipStream_t stream) {
    const float* hid    = (const float*)d_in[0];
    const float* W1     = (const float*)d_in[1];
    const float* b1     = (const float*)d_in[2];
    const float* ln_g   = (const float*)d_in[3];
    const float* ln_b   = (const float*)d_in[4];
    const float* W2     = (const float*)d_in[5];
    const float* b2     = (const float*)d_in[6];
    const float* qorig  = (const float*)d_in[7];
    const float* mem    = (const float*)d_in[8];
    const float* Wp     = (const float*)d_in[9];
    const float* bp     = (const float*)d_in[10];
    float* out = (float*)d_out;

    char* ws = (char*)d_ws;
    size_t off = 0;
    float* pp = (float*)(ws + off);       off += (size_t)B_ * SC_ * H_ * 4;       // 8 MB
    float* query = (float*)(ws + off);    off += (size_t)B_ * M_ * 4;
    float* qstats = (float*)(ws + off);   off += (size_t)B_ * 2 * 4;
    float* score = (float*)(ws + off);    off += (size_t)B_ * NPAD_ * 4;          // 64.2 MB
    float* cand_val = (float*)(ws + off); off += (size_t)NWIN_ * B_ * KK * 4;     // 0.5 MB
    int* cand_idx = (int*)(ws + off);     off += (size_t)NWIN_ * B_ * KK * 4;     // 0.5 MB
    int* topk_idx = (int*)(ws + off);     off += (size_t)B_ * KK * 4;
    float* force = (float*)(ws + off);    off += (size_t)B_ * H_ * 4;
    (void)ws_size; (void)in_sizes; (void)n_in; (void)out_size;

    hipLaunchKernelGGL(k1_pool, dim3(B_ * SC_), dim3(256), 0, stream, hid, pp);
    hipLaunchKernelGGL(k2_query, dim3(B_), dim3(128), 0, stream, pp, W1, b1, ln_g, ln_b,
                       W2, b2, qorig, query, qstats);
    hipLaunchKernelGGL(k3_scores, dim3(NBLK_), dim3(256), 0, stream, mem, query, qstats, score);
    hipLaunchKernelGGL(k4_sel, dim3(NWIN_), dim3(256), 0, stream, score, cand_val, cand_idx);
    hipLaunchKernelGGL(k4_merge, dim3(B_), dim3(256), 0, stream, cand_val, cand_idx, topk_idx);
    hipLaunchKernelGGL(k5_retrieve, dim3(B_), dim3(256), 0, stream, mem, query, qstats,
                       topk_idx, Wp, bp, force);
    hipLaunchKernelGGL(k6_out, dim3(2048), dim3(256), 0, stream, hid, force, out);
}

// Round 5
// 439.958 us; speedup vs baseline: 1.9010x; 1.0027x over previous
//
#include <hip/hip_runtime.h>
#include <float.h>
#include <math.h>

#define B_ 32
#define S_ 2048
#define H_ 1024
#define M_ 128
#define N_ 500000
#define KK 16
#define ALPHA_ 0.1f
#define TAU_ 0.1f
#define EPS_ 1e-5f
#define MAX_NORM_ 0.99999f
#define MAXN2_ (MAX_NORM_ * MAX_NORM_)
#define SC_ 64                       // pooling chunks over S
#define CH_ 512                      // memory rows per block in k3
#define NBLK_ ((N_ + CH_ - 1) / CH_) // 977
#define WIN_ 2048                    // selection window rows
#define NWIN_ ((N_ + WIN_ - 1) / WIN_) // 245
#define NPAD_ (NWIN_ * WIN_)         // 501760 padded plane stride

// ---------------------------------------------------------------- k1: pool partial sums
__global__ __launch_bounds__(256) void k1_pool(const float* __restrict__ hid,
                                               float* __restrict__ pp) {
    int bid = blockIdx.x;
    int b = bid >> 6, sc = bid & 63;
    const float4* h4 = (const float4*)hid;
    float4 acc = {0.f, 0.f, 0.f, 0.f};
    int s0 = sc * (S_ / SC_);
    for (int s = 0; s < S_ / SC_; ++s) {
        float4 v = h4[((size_t)(b * S_ + s0 + s) << 8) + threadIdx.x];
        acc.x += v.x; acc.y += v.y; acc.z += v.z; acc.w += v.w;
    }
    ((float4*)pp)[(size_t)(b * SC_ + sc) * 256 + threadIdx.x] = acc;
}

// ---------------------------------------------------------------- k2: query network (tiny)
__device__ __forceinline__ float block_reduce_sum_128(float v, volatile float* red, int tid) {
    red[tid] = v;
    __syncthreads();
    if (tid < 64) red[tid] += red[tid + 64];
    __syncthreads();
    if (tid < 64) {
        float x = red[tid];
        #pragma unroll
        for (int off = 32; off >= 1; off >>= 1) x += __shfl_down(x, off);
        if (tid == 0) red[0] = x;
    }
    __syncthreads();
    float r = red[0];
    __syncthreads();
    return r;
}

__global__ void k2_query(const float* __restrict__ pp, const float* __restrict__ W1,
                         const float* __restrict__ b1, const float* __restrict__ ln_g,
                         const float* __restrict__ ln_b, const float* __restrict__ W2,
                         const float* __restrict__ b2, const float* __restrict__ qorig,
                         float* __restrict__ query, float* __restrict__ qstats) {
    __shared__ float pooled[H_];
    __shared__ float red[128];
    __shared__ float hv[M_];
    int b = blockIdx.x, tid = threadIdx.x; // 128 threads
    #pragma unroll
    for (int j = 0; j < H_ / 128; ++j) {
        int h = tid + j * 128;
        float s = 0.f;
        for (int sc = 0; sc < SC_; ++sc) s += pp[(size_t)(b * SC_ + sc) * H_ + h];
        pooled[h] = s * (1.0f / (float)S_);
    }
    __syncthreads();
    int m = tid;
    float x = b1[m];
    for (int k = 0; k < H_; ++k) x = fmaf(pooled[k], W1[k * M_ + m], x);
    // layernorm
    float mu = block_reduce_sum_128(x, red, tid) * (1.0f / (float)M_);
    float dmu = x - mu;
    float var = block_reduce_sum_128(dmu * dmu, red, tid) * (1.0f / (float)M_);
    float xh = dmu * rsqrtf(var + 1e-5f) * ln_g[m] + ln_b[m];
    // exact gelu
    float g = 0.5f * xh * (1.0f + erff(xh * 0.70710678f));
    hv[m] = g;
    __syncthreads();
    float t = b2[m];
    for (int k = 0; k < M_; ++k) t = fmaf(hv[k], W2[k * M_ + m], t);
    // origin = project(q_origin)
    float o = qorig[m];
    float on2 = block_reduce_sum_128(o * o, red, tid);
    float on = fmaxf(sqrtf(on2), EPS_);
    float osc = 1.0f / fmaxf(on / MAX_NORM_, 1.0f);
    float u = o * osc;
    // exp_map second term
    float vn2 = block_reduce_sum_128(t * t, red, tid);
    float vn = fmaxf(sqrtf(vn2), EPS_);
    float sec = tanhf(vn * 0.5f) * t / vn;
    // mobius_add(u, sec)
    float dot_uv = block_reduce_sum_128(u * sec, red, tid);
    float nu = fminf(fmaxf(block_reduce_sum_128(u * u, red, tid), 0.f), MAXN2_);
    float nv = fminf(fmaxf(block_reduce_sum_128(sec * sec, red, tid), 0.f), MAXN2_);
    float num = (1.0f + 2.0f * dot_uv + nv) * u + (1.0f - nu) * sec;
    float den = 1.0f + 2.0f * dot_uv + nu * nv;
    float r = num / fmaxf(den, EPS_);
    // project
    float rn2 = block_reduce_sum_128(r * r, red, tid);
    float rn = fmaxf(sqrtf(rn2), EPS_);
    float rsc = 1.0f / fmaxf(rn / MAX_NORM_, 1.0f);
    float q = r * rsc;
    query[b * M_ + m] = q;
    float qq = block_reduce_sum_128(q * q, red, tid);
    if (tid == 0) {
        qstats[b * 2 + 0] = qq; // raw sum q*q (used in dist_sq)
        float qn = fminf(fmaxf(qq, 0.f), MAXN2_);
        qstats[b * 2 + 1] = 1.0f - qn; // (1 - qn_clipped)
    }
}

// ---------------------------------------------------------------- k3: pure streaming scorer
// No LDS. q/qstats read with wave-uniform indices -> scalar loads (SGPR),
// vector pipe does only row loads + FMA. Writes fp32 score planes [b][row].
// launch_bounds(256,4): cap VGPR at 128 so 4 waves/SIMD stay resident
// (64 accs + one 8-load group in flight; unroll 1 keeps regs bounded).
__global__ __launch_bounds__(256, 4) void k3_scores(const float* __restrict__ mem,
                                                    const float* __restrict__ query,
                                                    const float* __restrict__ qstats,
                                                    float* __restrict__ score) {
    int tid = threadIdx.x, bid = blockIdx.x;
    int r0 = bid * CH_ + tid;
    int r1 = r0 + 256;
    bool v0 = r0 < N_, v1 = r1 < N_;
    const float4* m0p = (const float4*)(mem + (size_t)(v0 ? r0 : 0) * M_);
    const float4* m1p = (const float4*)(mem + (size_t)(v1 ? r1 : 0) * M_);
    const float4* q4 = (const float4*)query;

    float acc0[B_], acc1[B_];
    #pragma unroll
    for (int b = 0; b < B_; ++b) { acc0[b] = 0.f; acc1[b] = 0.f; }
    float mm0 = 0.f, mm1 = 0.f;

    #pragma unroll 1
    for (int ko = 0; ko < 8; ++ko) {
        float4 a[4], c[4];
        #pragma unroll
        for (int i = 0; i < 4; ++i) { a[i] = m0p[ko * 4 + i]; }
        #pragma unroll
        for (int i = 0; i < 4; ++i) { c[i] = m1p[ko * 4 + i]; }
        #pragma unroll
        for (int i = 0; i < 4; ++i) {
            mm0 = fmaf(a[i].x, a[i].x, fmaf(a[i].y, a[i].y, fmaf(a[i].z, a[i].z, fmaf(a[i].w, a[i].w, mm0))));
            mm1 = fmaf(c[i].x, c[i].x, fmaf(c[i].y, c[i].y, fmaf(c[i].z, c[i].z, fmaf(c[i].w, c[i].w, mm1))));
        }
        #pragma unroll
        for (int b = 0; b < B_; ++b) {
            #pragma unroll
            for (int i = 0; i < 4; ++i) {
                float4 qv = q4[b * 32 + ko * 4 + i]; // wave-uniform -> s_load
                acc0[b] = fmaf(qv.x, a[i].x, fmaf(qv.y, a[i].y, fmaf(qv.z, a[i].z, fmaf(qv.w, a[i].w, acc0[b]))));
                acc1[b] = fmaf(qv.x, c[i].x, fmaf(qv.y, c[i].y, fmaf(qv.z, c[i].z, fmaf(qv.w, c[i].w, acc1[b]))));
            }
        }
    }

    float mn0 = fminf(mm0, MAXN2_), mn1 = fminf(mm1, MAXN2_);
    #pragma unroll
    for (int b = 0; b < B_; ++b) {
        float qq = qstats[b * 2];      // uniform -> scalar load
        float omq = qstats[b * 2 + 1];
        float ds0 = fmaxf(qq + mm0 - 2.0f * acc0[b], 0.f);
        float t0 = ds0 / fmaxf(omq * (1.0f - mn0), EPS_);
        float ds1 = fmaxf(qq + mm1 - 2.0f * acc1[b], 0.f);
        float t1 = ds1 / fmaxf(omq * (1.0f - mn1), EPS_);
        if (v0) score[(size_t)b * NPAD_ + r0] = t0;
        if (v1) score[(size_t)b * NPAD_ + r1] = t1;
    }
}

// ---------------------------------------------------------------- k4a: per-window top-16
// One block per 2048-row window. Each wave handles 8 batches alone: 32 keys/lane
// in registers, 16 extractions of wave-min over packed (quantized score | row).
__global__ __launch_bounds__(256, 4) void k4_sel(const float* __restrict__ score,
                                                 float* __restrict__ cand_val,
                                                 int* __restrict__ cand_idx) {
    int win = blockIdx.x; // 0..NWIN_-1
    int wave = threadIdx.x >> 6, lane = threadIdx.x & 63;
    int base = win * WIN_;
    #pragma unroll 2
    for (int j = 0; j < 8; ++j) {
        int b = wave * 8 + j;
        const float* sp = score + (size_t)b * NPAD_ + base;
        unsigned keys[32];
        #pragma unroll
        for (int i = 0; i < 32; ++i) {
            int lr = lane + i * 64;
            float v = sp[lr];
            unsigned kb = __float_as_uint(v); // v >= 0 -> bits monotone
            keys[i] = ((base + lr) < N_) ? ((kb & ~2047u) | (unsigned)lr) : 0xFFFFFFFFu;
        }
        for (int k = 0; k < KK; ++k) {
            unsigned m = keys[0];
            #pragma unroll
            for (int i = 1; i < 32; ++i) m = min(m, keys[i]);
            #pragma unroll
            for (int off = 32; off >= 1; off >>= 1)
                m = min(m, (unsigned)__shfl_xor((int)m, off));
            if (lane == 0) {
                cand_val[((size_t)win * B_ + b) * KK + k] = __uint_as_float(m & ~2047u);
                cand_idx[((size_t)win * B_ + b) * KK + k] = base + (int)(m & 2047u);
            }
            #pragma unroll
            for (int i = 0; i < 32; ++i)
                if (keys[i] == m) keys[i] = 0xFFFFFFFFu;
        }
    }
}

// ---------------------------------------------------------------- k45: merge windows + exact dists + softmax + retrieve + force
__global__ void k45_retrieve(const float* __restrict__ cand_val,
                             const int* __restrict__ cand_idx,
                             const float* __restrict__ mem, const float* __restrict__ query,
                             const float* __restrict__ qstats,
                             const float* __restrict__ Wp, const float* __restrict__ bp,
                             float* __restrict__ force) {
    __shared__ float tv[256 * KK];
    __shared__ int ti[256 * KK];
    __shared__ float mv[64 * KK];
    __shared__ int mi[64 * KK];
    __shared__ int topk_s[KK];
    __shared__ float q_s[M_];
    __shared__ float d_s[KK];
    __shared__ float w_s[KK];
    __shared__ float ret_s[M_];
    int b = blockIdx.x, tid = threadIdx.x; // 256 threads

    // ---- phase 1: per-thread gather of window candidates
    float val[KK]; int idx[KK];
    #pragma unroll
    for (int i = 0; i < KK; ++i) { val[i] = FLT_MAX; idx[i] = 0; }
    int nc = NWIN_ * KK; // 3920
    for (int c = tid; c < nc; c += 256) {
        int g = c >> 4, k = c & 15;
        float v = cand_val[((size_t)g * B_ + b) * KK + k];
        int id = cand_idx[((size_t)g * B_ + b) * KK + k];
        if (v < val[KK - 1]) {
            val[KK - 1] = v; idx[KK - 1] = id;
            #pragma unroll
            for (int j = KK - 1; j > 0; --j) {
                if (val[j] < val[j - 1]) {
                    float tvv = val[j]; val[j] = val[j - 1]; val[j - 1] = tvv;
                    int tii = idx[j]; idx[j] = idx[j - 1]; idx[j - 1] = tii;
                }
            }
        }
    }
    if (tid < M_) q_s[tid] = query[b * M_ + tid];
    #pragma unroll
    for (int i = 0; i < KK; ++i) { tv[tid * KK + i] = val[i]; ti[tid * KK + i] = idx[i]; }
    __syncthreads();

    // ---- phase 2: tree-merge on first wave
    if (tid < 64) {
        #pragma unroll
        for (int i = 0; i < KK; ++i) { val[i] = FLT_MAX; idx[i] = 0; }
        for (int t = tid * 4; t < tid * 4 + 4; ++t) {
            for (int i = 0; i < KK; ++i) { // source sorted ascending
                float v = tv[t * KK + i]; int id = ti[t * KK + i];
                if (v >= val[KK - 1]) break;
                val[KK - 1] = v; idx[KK - 1] = id;
                #pragma unroll
                for (int j = KK - 1; j > 0; --j) {
                    if (val[j] < val[j - 1]) {
                        float tvv = val[j]; val[j] = val[j - 1]; val[j - 1] = tvv;
                        int tii = idx[j]; idx[j] = idx[j - 1]; idx[j - 1] = tii;
                    }
                }
            }
        }
        #pragma unroll
        for (int i = 0; i < KK; ++i) { mv[tid * KK + i] = val[i]; mi[tid * KK + i] = idx[i]; }
        int h = 0;
        for (int k = 0; k < KK; ++k) {
            float cv = (h < KK) ? mv[tid * KK + h] : FLT_MAX;
            int ci = (h < KK) ? mi[tid * KK + h] : 0;
            float bestv = cv; int bestl = tid;
            #pragma unroll
            for (int off = 32; off >= 1; off >>= 1) {
                float ov = __shfl_down(bestv, off);
                int ol = __shfl_down(bestl, off);
                if (ov < bestv) { bestv = ov; bestl = ol; }
            }
            bestl = __shfl(bestl, 0);
            if (tid == bestl) {
                int id = ci;
                topk_s[k] = (id < 0) ? 0 : ((id >= N_) ? (N_ - 1) : id); // defensive clamp
                h++;
            }
        }
    }
    __syncthreads();

    // ---- phase 3: exact distances on the 16 finalists
    float qq = qstats[b * 2], omq = qstats[b * 2 + 1];
    int wave = tid >> 6, lane = tid & 63;
    for (int ii = wave; ii < KK; ii += 4) {
        const float* mr = mem + (size_t)topk_s[ii] * M_;
        float a0 = mr[lane], a1 = mr[lane + 64];
        float p = q_s[lane] * a0 + q_s[lane + 64] * a1;
        float mm = a0 * a0 + a1 * a1;
        #pragma unroll
        for (int off = 32; off >= 1; off >>= 1) {
            p += __shfl_down(p, off);
            mm += __shfl_down(mm, off);
        }
        if (lane == 0) {
            float dsq = fmaxf(qq + mm - 2.0f * p, 0.f);
            float mn = fminf(mm, MAXN2_);
            float t = dsq / fmaxf(omq * (1.0f - mn), EPS_);
            d_s[ii] = acoshf(1.0f + 2.0f * t);
        }
    }
    __syncthreads();
    if (tid == 0) {
        float dmin = d_s[0];
        for (int i = 1; i < KK; ++i) dmin = fminf(dmin, d_s[i]);
        float Z = 0.f;
        for (int i = 0; i < KK; ++i) {
            float w = expf((dmin - d_s[i]) * (1.0f / TAU_));
            w_s[i] = w; Z += w;
        }
        float iZ = 1.0f / Z;
        for (int i = 0; i < KK; ++i) w_s[i] *= iZ;
    }
    __syncthreads();
    // ---- phase 4: weighted retrieve + project to H
    if (tid < M_) {
        float r = 0.f;
        for (int i = 0; i < KK; ++i) r = fmaf(w_s[i], mem[(size_t)topk_s[i] * M_ + tid], r);
        ret_s[tid] = r;
    }
    __syncthreads();
    #pragma unroll
    for (int j = 0; j < 4; ++j) {
        int h = tid + j * 256;
        float f = bp[h];
        for (int k = 0; k < M_; ++k) f = fmaf(ret_s[k], Wp[k * H_ + h], f);
        force[b * H_ + h] = f;
    }
}

// ---------------------------------------------------------------- k6: out = hidden + alpha*force
__global__ __launch_bounds__(256) void k6_out(const float* __restrict__ hid,
                                              const float* __restrict__ force,
                                              float* __restrict__ out) {
    const float4* h4 = (const float4*)hid;
    const float4* f4 = (const float4*)force;
    float4* o4 = (float4*)out;
    int n4 = B_ * S_ * H_ / 4; // 16,777,216
    for (int i = blockIdx.x * blockDim.x + threadIdx.x; i < n4; i += gridDim.x * blockDim.x) {
        int b = i >> 19; // (S*H/4) = 2^19
        float4 hv = h4[i];
        float4 fv = f4[(b << 8) + (i & 255)];
        float4 ov;
        ov.x = fmaf(ALPHA_, fv.x, hv.x);
        ov.y = fmaf(ALPHA_, fv.y, hv.y);
        ov.z = fmaf(ALPHA_, fv.z, hv.z);
        ov.w = fmaf(ALPHA_, fv.w, hv.w);
        o4[i] = ov;
    }
}

// ---------------------------------------------------------------- launch
extern "C" void kernel_launch(void* const* d_in, const int* in_sizes, int n_in,
                              void* d_out, int out_size, void* d_ws, size_t ws_size,
                              hipStream_t stream) {
    const float* hid    = (const float*)d_in[0];
    const float* W1     = (const float*)d_in[1];
    const float* b1     = (const float*)d_in[2];
    const float* ln_g   = (const float*)d_in[3];
    const float* ln_b   = (const float*)d_in[4];
    const float* W2     = (const float*)d_in[5];
    const float* b2     = (const float*)d_in[6];
    const float* qorig  = (const float*)d_in[7];
    const float* mem    = (const float*)d_in[8];
    const float* Wp     = (const float*)d_in[9];
    const float* bp     = (const float*)d_in[10];
    float* out = (float*)d_out;

    char* ws = (char*)d_ws;
    size_t off = 0;
    float* pp = (float*)(ws + off);       off += (size_t)B_ * SC_ * H_ * 4;       // 8 MB
    float* query = (float*)(ws + off);    off += (size_t)B_ * M_ * 4;
    float* qstats = (float*)(ws + off);   off += (size_t)B_ * 2 * 4;
    float* score = (float*)(ws + off);    off += (size_t)B_ * NPAD_ * 4;          // 64.2 MB
    float* cand_val = (float*)(ws + off); off += (size_t)NWIN_ * B_ * KK * 4;     // 0.5 MB
    int* cand_idx = (int*)(ws + off);     off += (size_t)NWIN_ * B_ * KK * 4;     // 0.5 MB
    float* force = (float*)(ws + off);    off += (size_t)B_ * H_ * 4;
    (void)ws_size; (void)in_sizes; (void)n_in; (void)out_size;

    hipLaunchKernelGGL(k1_pool, dim3(B_ * SC_), dim3(256), 0, stream, hid, pp);
    hipLaunchKernelGGL(k2_query, dim3(B_), dim3(128), 0, stream, pp, W1, b1, ln_g, ln_b,
                       W2, b2, qorig, query, qstats);
    hipLaunchKernelGGL(k3_scores, dim3(NBLK_), dim3(256), 0, stream, mem, query, qstats, score);
    hipLaunchKernelGGL(k4_sel, dim3(NWIN_), dim3(256), 0, stream, score, cand_val, cand_idx);
    hipLaunchKernelGGL(k45_retrieve, dim3(B_), dim3(256), 0, stream, cand_val, cand_idx,
                       mem, query, qstats, Wp, bp, force);
    hipLaunchKernelGGL(k6_out, dim3(2048), dim3(256), 0, stream, hid, force, out);
}

// Round 6
// 427.703 us; speedup vs baseline: 1.9554x; 1.0287x over previous
//
#include <hip/hip_runtime.h>
#include <float.h>
#include <math.h>

#define B_ 32
#define S_ 2048
#define H_ 1024
#define M_ 128
#define N_ 500000
#define KK 16
#define KK2 32
#define ALPHA_ 0.1f
#define TAU_ 0.1f
#define EPS_ 1e-5f
#define MAX_NORM_ 0.99999f
#define MAXN2_ (MAX_NORM_ * MAX_NORM_)
#define SC_ 64                         // pooling chunks over S
#define RPB_ 512                       // rows per block in k3
#define NBLK_ ((N_ + RPB_ - 1) / RPB_) // 977
#define WIN_ 2048                      // selection window rows
#define NWIN_ ((N_ + WIN_ - 1) / WIN_) // 245
#define NPAD_ (NWIN_ * WIN_)           // 501760 padded plane stride

typedef __attribute__((ext_vector_type(8))) short short8;
typedef __attribute__((ext_vector_type(4))) float f32x4;

__device__ __forceinline__ unsigned short to_bf16(float x) {
    unsigned u = __float_as_uint(x);
    return (unsigned short)((u + 0x7FFFu + ((u >> 16) & 1u)) >> 16); // RNE
}

// ---------------------------------------------------------------- k1: pool partial sums
__global__ __launch_bounds__(256) void k1_pool(const float* __restrict__ hid,
                                               float* __restrict__ pp) {
    int bid = blockIdx.x;
    int b = bid >> 6, sc = bid & 63;
    const float4* h4 = (const float4*)hid;
    float4 acc = {0.f, 0.f, 0.f, 0.f};
    int s0 = sc * (S_ / SC_);
    for (int s = 0; s < S_ / SC_; ++s) {
        float4 v = h4[((size_t)(b * S_ + s0 + s) << 8) + threadIdx.x];
        acc.x += v.x; acc.y += v.y; acc.z += v.z; acc.w += v.w;
    }
    ((float4*)pp)[(size_t)(b * SC_ + sc) * 256 + threadIdx.x] = acc;
}

// ---------------------------------------------------------------- k2: query network (tiny)
__device__ __forceinline__ float block_reduce_sum_128(float v, volatile float* red, int tid) {
    red[tid] = v;
    __syncthreads();
    if (tid < 64) red[tid] += red[tid + 64];
    __syncthreads();
    if (tid < 64) {
        float x = red[tid];
        #pragma unroll
        for (int off = 32; off >= 1; off >>= 1) x += __shfl_down(x, off);
        if (tid == 0) red[0] = x;
    }
    __syncthreads();
    float r = red[0];
    __syncthreads();
    return r;
}

__global__ void k2_query(const float* __restrict__ pp, const float* __restrict__ W1,
                         const float* __restrict__ b1, const float* __restrict__ ln_g,
                         const float* __restrict__ ln_b, const float* __restrict__ W2,
                         const float* __restrict__ b2, const float* __restrict__ qorig,
                         float* __restrict__ query, float* __restrict__ qstats) {
    __shared__ float pooled[H_];
    __shared__ float red[128];
    __shared__ float hv[M_];
    int b = blockIdx.x, tid = threadIdx.x; // 128 threads
    #pragma unroll
    for (int j = 0; j < H_ / 128; ++j) {
        int h = tid + j * 128;
        float s = 0.f;
        for (int sc = 0; sc < SC_; ++sc) s += pp[(size_t)(b * SC_ + sc) * H_ + h];
        pooled[h] = s * (1.0f / (float)S_);
    }
    __syncthreads();
    int m = tid;
    float x = b1[m];
    for (int k = 0; k < H_; ++k) x = fmaf(pooled[k], W1[k * M_ + m], x);
    float mu = block_reduce_sum_128(x, red, tid) * (1.0f / (float)M_);
    float dmu = x - mu;
    float var = block_reduce_sum_128(dmu * dmu, red, tid) * (1.0f / (float)M_);
    float xh = dmu * rsqrtf(var + 1e-5f) * ln_g[m] + ln_b[m];
    float g = 0.5f * xh * (1.0f + erff(xh * 0.70710678f));
    hv[m] = g;
    __syncthreads();
    float t = b2[m];
    for (int k = 0; k < M_; ++k) t = fmaf(hv[k], W2[k * M_ + m], t);
    float o = qorig[m];
    float on2 = block_reduce_sum_128(o * o, red, tid);
    float on = fmaxf(sqrtf(on2), EPS_);
    float osc = 1.0f / fmaxf(on / MAX_NORM_, 1.0f);
    float u = o * osc;
    float vn2 = block_reduce_sum_128(t * t, red, tid);
    float vn = fmaxf(sqrtf(vn2), EPS_);
    float sec = tanhf(vn * 0.5f) * t / vn;
    float dot_uv = block_reduce_sum_128(u * sec, red, tid);
    float nu = fminf(fmaxf(block_reduce_sum_128(u * u, red, tid), 0.f), MAXN2_);
    float nv = fminf(fmaxf(block_reduce_sum_128(sec * sec, red, tid), 0.f), MAXN2_);
    float num = (1.0f + 2.0f * dot_uv + nv) * u + (1.0f - nu) * sec;
    float den = 1.0f + 2.0f * dot_uv + nu * nv;
    float r = num / fmaxf(den, EPS_);
    float rn2 = block_reduce_sum_128(r * r, red, tid);
    float rn = fmaxf(sqrtf(rn2), EPS_);
    float rsc = 1.0f / fmaxf(rn / MAX_NORM_, 1.0f);
    float q = r * rsc;
    query[b * M_ + m] = q;
    float qq = block_reduce_sum_128(q * q, red, tid);
    if (tid == 0) {
        qstats[b * 2 + 0] = qq;
        float qn = fminf(fmaxf(qq, 0.f), MAXN2_);
        qstats[b * 2 + 1] = 1.0f - qn;
    }
}

// ---------------------------------------------------------------- k3: MFMA scorer -> packed keys
// Dots via mfma_f32_16x16x32_bf16 (A = mem rows bf16, B = query bf16, fp32 acc).
// Row norms mm in fp32 from pre-conversion data. Writes u32 keys
// (score_bits & ~2047) | (row & 2047) into [b][row] planes (coalesced via LDS transpose).
__global__ __launch_bounds__(256, 4) void k3_scores(const float* __restrict__ mem,
                                                    const float* __restrict__ query,
                                                    const float* __restrict__ qstats,
                                                    unsigned* __restrict__ keyplane) {
    __shared__ unsigned key_lds[B_][260];   // 260: 16B-aligned rows, low bank conflict
    __shared__ float mm_lds[256];
    __shared__ float qq_s[B_], omq_s[B_];
    int tid = threadIdx.x, bid = blockIdx.x;
    int wave = tid >> 6, lane = tid & 63;
    int l15 = lane & 15, lk = lane >> 4;

    if (tid < B_) { qq_s[tid] = qstats[tid * 2]; omq_s[tid] = qstats[tid * 2 + 1]; }

    // B fragments (query), built once: batch = bg*16+l15, k = kt*32 + lk*8 + j
    short8 bfrag[2][4];
    #pragma unroll
    for (int bg = 0; bg < 2; ++bg) {
        #pragma unroll
        for (int kt = 0; kt < 4; ++kt) {
            int batch = bg * 16 + l15;
            const float4* qp = (const float4*)(query + batch * M_ + kt * 32 + lk * 8);
            float4 lo = qp[0], hi = qp[1];
            short8 f;
            f[0] = (short)to_bf16(lo.x); f[1] = (short)to_bf16(lo.y);
            f[2] = (short)to_bf16(lo.z); f[3] = (short)to_bf16(lo.w);
            f[4] = (short)to_bf16(hi.x); f[5] = (short)to_bf16(hi.y);
            f[6] = (short)to_bf16(hi.z); f[7] = (short)to_bf16(hi.w);
            bfrag[bg][kt] = f;
        }
    }

    #pragma unroll 1
    for (int p = 0; p < 2; ++p) {
        int passbase = bid * RPB_ + p * 256; // global row base of this pass
        f32x4 acc[4][2];
        #pragma unroll
        for (int rg = 0; rg < 4; ++rg)
            #pragma unroll
            for (int bg = 0; bg < 2; ++bg)
                acc[rg][bg] = (f32x4){0.f, 0.f, 0.f, 0.f};
        float mmp[4] = {0.f, 0.f, 0.f, 0.f};

        #pragma unroll 1
        for (int rg = 0; rg < 4; ++rg) {
            int r = passbase + wave * 64 + rg * 16 + l15;
            const float4* mp = (const float4*)(mem + (size_t)((r < N_) ? r : 0) * M_);
            #pragma unroll
            for (int kt = 0; kt < 4; ++kt) {
                float4 lo = mp[kt * 8 + lk * 2];
                float4 hi = mp[kt * 8 + lk * 2 + 1];
                mmp[rg] = fmaf(lo.x, lo.x, fmaf(lo.y, lo.y, fmaf(lo.z, lo.z, fmaf(lo.w, lo.w, mmp[rg]))));
                mmp[rg] = fmaf(hi.x, hi.x, fmaf(hi.y, hi.y, fmaf(hi.z, hi.z, fmaf(hi.w, hi.w, mmp[rg]))));
                short8 af;
                af[0] = (short)to_bf16(lo.x); af[1] = (short)to_bf16(lo.y);
                af[2] = (short)to_bf16(lo.z); af[3] = (short)to_bf16(lo.w);
                af[4] = (short)to_bf16(hi.x); af[5] = (short)to_bf16(hi.y);
                af[6] = (short)to_bf16(hi.z); af[7] = (short)to_bf16(hi.w);
                acc[rg][0] = __builtin_amdgcn_mfma_f32_16x16x32_bf16(af, bfrag[0][kt], acc[rg][0], 0, 0, 0);
                acc[rg][1] = __builtin_amdgcn_mfma_f32_16x16x32_bf16(af, bfrag[1][kt], acc[rg][1], 0, 0, 0);
            }
        }
        // reduce row norms across the 4 k-groups and stage per-row
        #pragma unroll
        for (int rg = 0; rg < 4; ++rg) {
            float v = mmp[rg] + __shfl_xor(mmp[rg], 16);
            v += __shfl_xor(v, 32);
            if (lane < 16) mm_lds[wave * 64 + rg * 16 + l15] = v;
        }
        __syncthreads();

        // epilogue: score -> packed key into LDS [batch][row_local]
        #pragma unroll
        for (int rg = 0; rg < 4; ++rg) {
            #pragma unroll
            for (int bg = 0; bg < 2; ++bg) {
                #pragma unroll
                for (int reg = 0; reg < 4; ++reg) {
                    int row_local = wave * 64 + rg * 16 + lk * 4 + reg;
                    int batch = bg * 16 + l15;
                    float dot = acc[rg][bg][reg];
                    float mmv = mm_lds[row_local];
                    float mn = fminf(mmv, MAXN2_);
                    float dsq = fmaxf(qq_s[batch] + mmv - 2.0f * dot, 0.f);
                    float t = dsq / fmaxf(omq_s[batch] * (1.0f - mn), EPS_);
                    int grow = passbase + row_local;
                    unsigned key = (__float_as_uint(t) & ~2047u) | ((unsigned)grow & 2047u);
                    key_lds[batch][row_local] = key;
                }
            }
        }
        __syncthreads();

        // transpose-write to global: coalesced per-batch row runs
        {
            int batch = tid >> 3, chunk = tid & 7;
            int rbase = passbase + chunk * 32;
            unsigned* dstp = keyplane + (size_t)batch * NPAD_ + rbase;
            #pragma unroll
            for (int i = 0; i < 8; ++i) {
                int rl = chunk * 32 + i * 4;
                uint4 v = *(const uint4*)&key_lds[batch][rl];
                int gr = rbase + i * 4;
                if (gr + 4 <= N_) {
                    *(uint4*)(dstp + i * 4) = v;
                } else {
                    if (gr + 0 < N_) dstp[i * 4 + 0] = v.x;
                    if (gr + 1 < N_) dstp[i * 4 + 1] = v.y;
                    if (gr + 2 < N_) dstp[i * 4 + 2] = v.z;
                    if (gr + 3 < N_) dstp[i * 4 + 3] = v.w;
                }
            }
        }
        __syncthreads();
    }
}

// ---------------------------------------------------------------- k4: per-window top-16 (u32 keys)
// 980 blocks = (window, quad); each wave owns 2 batches, 32 keys/lane in regs.
__global__ __launch_bounds__(256, 4) void k4_sel(const unsigned* __restrict__ keyplane,
                                                 unsigned* __restrict__ cand_key) {
    int win = blockIdx.x >> 2, quad = blockIdx.x & 3;
    int wave = threadIdx.x >> 6, lane = threadIdx.x & 63;
    int base = win * WIN_;
    #pragma unroll 1
    for (int j = 0; j < 2; ++j) {
        int b = quad * 8 + wave * 2 + j;
        const uint4* kp = (const uint4*)(keyplane + (size_t)b * NPAD_ + base);
        unsigned keys[32];
        #pragma unroll
        for (int i = 0; i < 8; ++i) {
            uint4 v = kp[lane + i * 64];
            int pos = base + (lane + i * 64) * 4;
            keys[i * 4 + 0] = (pos + 0 < N_) ? v.x : 0xFFFFFFFFu;
            keys[i * 4 + 1] = (pos + 1 < N_) ? v.y : 0xFFFFFFFFu;
            keys[i * 4 + 2] = (pos + 2 < N_) ? v.z : 0xFFFFFFFFu;
            keys[i * 4 + 3] = (pos + 3 < N_) ? v.w : 0xFFFFFFFFu;
        }
        for (int k = 0; k < KK; ++k) {
            unsigned m = keys[0];
            #pragma unroll
            for (int i = 1; i < 32; ++i) m = min(m, keys[i]);
            #pragma unroll
            for (int off = 32; off >= 1; off >>= 1)
                m = min(m, (unsigned)__shfl_xor((int)m, off));
            if (lane == 0) cand_key[((size_t)win * B_ + b) * KK + k] = m;
            #pragma unroll
            for (int i = 0; i < 32; ++i)
                if (keys[i] == m) keys[i] = 0xFFFFFFFFu;
        }
    }
}

// ---------------------------------------------------------------- k45: merge->32, exact dists, exact top-16, softmax, retrieve, force
__global__ void k45_retrieve(const unsigned* __restrict__ cand_key,
                             const float* __restrict__ mem, const float* __restrict__ query,
                             const float* __restrict__ qstats,
                             const float* __restrict__ Wp, const float* __restrict__ bp,
                             float* __restrict__ force) {
    __shared__ unsigned tv[256 * KK];
    __shared__ int ti[256 * KK];
    __shared__ unsigned mv[64 * KK];
    __shared__ int mi[64 * KK];
    __shared__ int top32_s[KK2];
    __shared__ float q_s[M_];
    __shared__ float d_s[KK2];
    __shared__ float w_s[KK];
    __shared__ int idx_s[KK];
    __shared__ float ret_s[M_];
    int b = blockIdx.x, tid = threadIdx.x; // 256 threads

    // phase 1: per-thread insertion top-16 over all window candidates
    unsigned val[KK]; int idx[KK];
    #pragma unroll
    for (int i = 0; i < KK; ++i) { val[i] = 0xFFFFFFFFu; idx[i] = 0; }
    int nc = NWIN_ * KK; // 3920
    for (int c = tid; c < nc; c += 256) {
        int g = c >> 4, k = c & 15;
        unsigned v = cand_key[((size_t)g * B_ + b) * KK + k];
        int id = g * WIN_ + (int)(v & 2047u);
        if (v < val[KK - 1]) {
            val[KK - 1] = v; idx[KK - 1] = id;
            #pragma unroll
            for (int j = KK - 1; j > 0; --j) {
                if (val[j] < val[j - 1]) {
                    unsigned tvv = val[j]; val[j] = val[j - 1]; val[j - 1] = tvv;
                    int tii = idx[j]; idx[j] = idx[j - 1]; idx[j - 1] = tii;
                }
            }
        }
    }
    if (tid < M_) q_s[tid] = query[b * M_ + tid];
    #pragma unroll
    for (int i = 0; i < KK; ++i) { tv[tid * KK + i] = val[i]; ti[tid * KK + i] = idx[i]; }
    __syncthreads();

    // phase 2: tree-merge to approx top-32 on wave 0
    if (tid < 64) {
        #pragma unroll
        for (int i = 0; i < KK; ++i) { val[i] = 0xFFFFFFFFu; idx[i] = 0; }
        for (int t = tid * 4; t < tid * 4 + 4; ++t) {
            for (int i = 0; i < KK; ++i) {
                unsigned v = tv[t * KK + i]; int id = ti[t * KK + i];
                if (v >= val[KK - 1]) break;
                val[KK - 1] = v; idx[KK - 1] = id;
                #pragma unroll
                for (int j = KK - 1; j > 0; --j) {
                    if (val[j] < val[j - 1]) {
                        unsigned tvv = val[j]; val[j] = val[j - 1]; val[j - 1] = tvv;
                        int tii = idx[j]; idx[j] = idx[j - 1]; idx[j - 1] = tii;
                    }
                }
            }
        }
        #pragma unroll
        for (int i = 0; i < KK; ++i) { mv[tid * KK + i] = val[i]; mi[tid * KK + i] = idx[i]; }
        int h = 0;
        for (int k = 0; k < KK2; ++k) {
            unsigned cv = (h < KK) ? mv[tid * KK + h] : 0xFFFFFFFFu;
            int ci = (h < KK) ? mi[tid * KK + h] : 0;
            unsigned bestv = cv; int bestl = tid;
            #pragma unroll
            for (int off = 32; off >= 1; off >>= 1) {
                unsigned ov = (unsigned)__shfl_down((int)bestv, off);
                int ol = __shfl_down(bestl, off);
                if (ov < bestv) { bestv = ov; bestl = ol; }
            }
            bestl = __shfl(bestl, 0);
            if (tid == bestl) {
                top32_s[k] = (ci < 0) ? 0 : ((ci >= N_) ? (N_ - 1) : ci);
                h++;
            }
        }
    }
    __syncthreads();

    // phase 3: exact distances on the 32 finalists
    float qq = qstats[b * 2], omq = qstats[b * 2 + 1];
    int wave = tid >> 6, lane = tid & 63;
    for (int ii = wave; ii < KK2; ii += 4) {
        const float* mr = mem + (size_t)top32_s[ii] * M_;
        float a0 = mr[lane], a1 = mr[lane + 64];
        float p = q_s[lane] * a0 + q_s[lane + 64] * a1;
        float mm = a0 * a0 + a1 * a1;
        #pragma unroll
        for (int off = 32; off >= 1; off >>= 1) {
            p += __shfl_down(p, off);
            mm += __shfl_down(mm, off);
        }
        if (lane == 0) {
            float dsq = fmaxf(qq + mm - 2.0f * p, 0.f);
            float mn = fminf(mm, MAXN2_);
            float t = dsq / fmaxf(omq * (1.0f - mn), EPS_);
            d_s[ii] = acoshf(1.0f + 2.0f * t);
        }
    }
    __syncthreads();
    // exact top-16 of the 32 (tie-break by memory index), then softmax
    if (tid == 0) {
        bool used[KK2];
        for (int i = 0; i < KK2; ++i) used[i] = false;
        float seld[KK];
        for (int k = 0; k < KK; ++k) {
            float bd = FLT_MAX; int bi = -1;
            for (int i = 0; i < KK2; ++i) {
                if (used[i]) continue;
                if (d_s[i] < bd || (d_s[i] == bd && (bi < 0 || top32_s[i] < top32_s[bi]))) {
                    bd = d_s[i]; bi = i;
                }
            }
            used[bi] = true; seld[k] = bd; idx_s[k] = top32_s[bi];
        }
        float dmin = seld[0];
        for (int i = 1; i < KK; ++i) dmin = fminf(dmin, seld[i]);
        float Z = 0.f;
        for (int i = 0; i < KK; ++i) {
            float w = expf((dmin - seld[i]) * (1.0f / TAU_));
            w_s[i] = w; Z += w;
        }
        float iZ = 1.0f / Z;
        for (int i = 0; i < KK; ++i) w_s[i] *= iZ;
    }
    __syncthreads();
    // phase 4: weighted retrieve + project to H
    if (tid < M_) {
        float r = 0.f;
        for (int i = 0; i < KK; ++i) r = fmaf(w_s[i], mem[(size_t)idx_s[i] * M_ + tid], r);
        ret_s[tid] = r;
    }
    __syncthreads();
    #pragma unroll
    for (int j = 0; j < 4; ++j) {
        int h = tid + j * 256;
        float f = bp[h];
        for (int k = 0; k < M_; ++k) f = fmaf(ret_s[k], Wp[k * H_ + h], f);
        force[b * H_ + h] = f;
    }
}

// ---------------------------------------------------------------- k6: out = hidden + alpha*force
__global__ __launch_bounds__(256) void k6_out(const float* __restrict__ hid,
                                              const float* __restrict__ force,
                                              float* __restrict__ out) {
    const float4* h4 = (const float4*)hid;
    const float4* f4 = (const float4*)force;
    float4* o4 = (float4*)out;
    int n4 = B_ * S_ * H_ / 4; // 16,777,216
    for (int i = blockIdx.x * blockDim.x + threadIdx.x; i < n4; i += gridDim.x * blockDim.x) {
        int b = i >> 19; // (S*H/4) = 2^19
        float4 hv = h4[i];
        float4 fv = f4[(b << 8) + (i & 255)];
        float4 ov;
        ov.x = fmaf(ALPHA_, fv.x, hv.x);
        ov.y = fmaf(ALPHA_, fv.y, hv.y);
        ov.z = fmaf(ALPHA_, fv.z, hv.z);
        ov.w = fmaf(ALPHA_, fv.w, hv.w);
        o4[i] = ov;
    }
}

// ---------------------------------------------------------------- launch
extern "C" void kernel_launch(void* const* d_in, const int* in_sizes, int n_in,
                              void* d_out, int out_size, void* d_ws, size_t ws_size,
                              hipStream_t stream) {
    const float* hid    = (const float*)d_in[0];
    const float* W1     = (const float*)d_in[1];
    const float* b1     = (const float*)d_in[2];
    const float* ln_g   = (const float*)d_in[3];
    const float* ln_b   = (const float*)d_in[4];
    const float* W2     = (const float*)d_in[5];
    const float* b2     = (const float*)d_in[6];
    const float* qorig  = (const float*)d_in[7];
    const float* mem    = (const float*)d_in[8];
    const float* Wp     = (const float*)d_in[9];
    const float* bp     = (const float*)d_in[10];
    float* out = (float*)d_out;

    char* ws = (char*)d_ws;
    size_t off = 0;
    float* pp = (float*)(ws + off);        off += (size_t)B_ * SC_ * H_ * 4;   // 8 MB
    float* query = (float*)(ws + off);     off += (size_t)B_ * M_ * 4;
    float* qstats = (float*)(ws + off);    off += (size_t)B_ * 2 * 4;
    off = (off + 255) & ~(size_t)255;
    unsigned* keyplane = (unsigned*)(ws + off); off += (size_t)B_ * NPAD_ * 4;  // 64.2 MB
    unsigned* cand_key = (unsigned*)(ws + off); off += (size_t)NWIN_ * B_ * KK * 4;
    float* force = (float*)(ws + off);     off += (size_t)B_ * H_ * 4;
    (void)ws_size; (void)in_sizes; (void)n_in; (void)out_size;

    hipLaunchKernelGGL(k1_pool, dim3(B_ * SC_), dim3(256), 0, stream, hid, pp);
    hipLaunchKernelGGL(k2_query, dim3(B_), dim3(128), 0, stream, pp, W1, b1, ln_g, ln_b,
                       W2, b2, qorig, query, qstats);
    hipLaunchKernelGGL(k3_scores, dim3(NBLK_), dim3(256), 0, stream, mem, query, qstats, keyplane);
    hipLaunchKernelGGL(k4_sel, dim3(NWIN_ * 4), dim3(256), 0, stream, keyplane, cand_key);
    hipLaunchKernelGGL(k45_retrieve, dim3(B_), dim3(256), 0, stream, cand_key,
                       mem, query, qstats, Wp, bp, force);
    hipLaunchKernelGGL(k6_out, dim3(2048), dim3(256), 0, stream, hid, force, out);
}

// Round 7
// 418.940 us; speedup vs baseline: 1.9963x; 1.0209x over previous
//
#include <hip/hip_runtime.h>
#include <float.h>
#include <math.h>

#define B_ 32
#define S_ 2048
#define H_ 1024
#define M_ 128
#define N_ 500000
#define KK 16
#define KK2 32
#define ALPHA_ 0.1f
#define TAU_ 0.1f
#define EPS_ 1e-5f
#define MAX_NORM_ 0.99999f
#define MAXN2_ (MAX_NORM_ * MAX_NORM_)
#define SC_ 64                         // pooling chunks over S
#define RPB_ 512                       // rows per block in k3
#define NBLK_ ((N_ + RPB_ - 1) / RPB_) // 977
#define WIN_ 2048                      // selection window rows
#define NWIN_ ((N_ + WIN_ - 1) / WIN_) // 245
#define NPAD_ (NWIN_ * WIN_)           // 501760 padded plane stride (ushort elems)

typedef __attribute__((ext_vector_type(8))) short short8;
typedef __attribute__((ext_vector_type(4))) float f32x4;

__device__ __forceinline__ unsigned short to_bf16(float x) {
    unsigned u = __float_as_uint(x);
    return (unsigned short)((u + 0x7FFFu + ((u >> 16) & 1u)) >> 16); // RNE, monotone on +floats
}

// ---------------------------------------------------------------- k1: pool partial sums
__global__ __launch_bounds__(256) void k1_pool(const float* __restrict__ hid,
                                               float* __restrict__ pp) {
    int bid = blockIdx.x;
    int b = bid >> 6, sc = bid & 63;
    const float4* h4 = (const float4*)hid;
    float4 acc = {0.f, 0.f, 0.f, 0.f};
    int s0 = sc * (S_ / SC_);
    for (int s = 0; s < S_ / SC_; ++s) {
        float4 v = h4[((size_t)(b * S_ + s0 + s) << 8) + threadIdx.x];
        acc.x += v.x; acc.y += v.y; acc.z += v.z; acc.w += v.w;
    }
    ((float4*)pp)[(size_t)(b * SC_ + sc) * 256 + threadIdx.x] = acc;
}

// ---------------------------------------------------------------- k2: query network (tiny)
__device__ __forceinline__ float block_reduce_sum_128(float v, volatile float* red, int tid) {
    red[tid] = v;
    __syncthreads();
    if (tid < 64) red[tid] += red[tid + 64];
    __syncthreads();
    if (tid < 64) {
        float x = red[tid];
        #pragma unroll
        for (int off = 32; off >= 1; off >>= 1) x += __shfl_down(x, off);
        if (tid == 0) red[0] = x;
    }
    __syncthreads();
    float r = red[0];
    __syncthreads();
    return r;
}

__global__ void k2_query(const float* __restrict__ pp, const float* __restrict__ W1,
                         const float* __restrict__ b1, const float* __restrict__ ln_g,
                         const float* __restrict__ ln_b, const float* __restrict__ W2,
                         const float* __restrict__ b2, const float* __restrict__ qorig,
                         float* __restrict__ query, float* __restrict__ qstats) {
    __shared__ float pooled[H_];
    __shared__ float red[128];
    __shared__ float hv[M_];
    int b = blockIdx.x, tid = threadIdx.x; // 128 threads
    #pragma unroll
    for (int j = 0; j < H_ / 128; ++j) {
        int h = tid + j * 128;
        float s = 0.f;
        for (int sc = 0; sc < SC_; ++sc) s += pp[(size_t)(b * SC_ + sc) * H_ + h];
        pooled[h] = s * (1.0f / (float)S_);
    }
    __syncthreads();
    int m = tid;
    float x = b1[m];
    for (int k = 0; k < H_; ++k) x = fmaf(pooled[k], W1[k * M_ + m], x);
    float mu = block_reduce_sum_128(x, red, tid) * (1.0f / (float)M_);
    float dmu = x - mu;
    float var = block_reduce_sum_128(dmu * dmu, red, tid) * (1.0f / (float)M_);
    float xh = dmu * rsqrtf(var + 1e-5f) * ln_g[m] + ln_b[m];
    float g = 0.5f * xh * (1.0f + erff(xh * 0.70710678f));
    hv[m] = g;
    __syncthreads();
    float t = b2[m];
    for (int k = 0; k < M_; ++k) t = fmaf(hv[k], W2[k * M_ + m], t);
    float o = qorig[m];
    float on2 = block_reduce_sum_128(o * o, red, tid);
    float on = fmaxf(sqrtf(on2), EPS_);
    float osc = 1.0f / fmaxf(on / MAX_NORM_, 1.0f);
    float u = o * osc;
    float vn2 = block_reduce_sum_128(t * t, red, tid);
    float vn = fmaxf(sqrtf(vn2), EPS_);
    float sec = tanhf(vn * 0.5f) * t / vn;
    float dot_uv = block_reduce_sum_128(u * sec, red, tid);
    float nu = fminf(fmaxf(block_reduce_sum_128(u * u, red, tid), 0.f), MAXN2_);
    float nv = fminf(fmaxf(block_reduce_sum_128(sec * sec, red, tid), 0.f), MAXN2_);
    float num = (1.0f + 2.0f * dot_uv + nv) * u + (1.0f - nu) * sec;
    float den = 1.0f + 2.0f * dot_uv + nu * nv;
    float r = num / fmaxf(den, EPS_);
    float rn2 = block_reduce_sum_128(r * r, red, tid);
    float rn = fmaxf(sqrtf(rn2), EPS_);
    float rsc = 1.0f / fmaxf(rn / MAX_NORM_, 1.0f);
    float q = r * rsc;
    query[b * M_ + m] = q;
    float qq = block_reduce_sum_128(q * q, red, tid);
    if (tid == 0) {
        qstats[b * 2 + 0] = qq;
        float qn = fminf(fmaxf(qq, 0.f), MAXN2_);
        qstats[b * 2 + 1] = 1.0f - qn;
    }
}

// ---------------------------------------------------------------- k3: MFMA scorer -> ushort score planes
// Fully-unrolled rg/kt so acc/bfrag/mmp are all static-indexed (VGPR-resident, rule #20).
// Writes 16-bit monotone score keys into [b][row] planes (coalesced via LDS transpose).
__global__ __launch_bounds__(256, 3) void k3_scores(const float* __restrict__ mem,
                                                    const float* __restrict__ query,
                                                    const float* __restrict__ qstats,
                                                    unsigned short* __restrict__ keyplane) {
    __shared__ unsigned short key_lds[B_][264]; // 16B-aligned rows
    __shared__ float mm_lds[256];
    __shared__ float qq_s[B_], omq_s[B_];
    int tid = threadIdx.x, bid = blockIdx.x;
    int wave = tid >> 6, lane = tid & 63;
    int l15 = lane & 15, lk = lane >> 4;

    if (tid < B_) { qq_s[tid] = qstats[tid * 2]; omq_s[tid] = qstats[tid * 2 + 1]; }

    // B fragments (query), built once: batch = bg*16+l15, k = kt*32 + lk*8 + j
    short8 bfrag[2][4];
    #pragma unroll
    for (int bg = 0; bg < 2; ++bg) {
        #pragma unroll
        for (int kt = 0; kt < 4; ++kt) {
            int batch = bg * 16 + l15;
            const float4* qp = (const float4*)(query + batch * M_ + kt * 32 + lk * 8);
            float4 lo = qp[0], hi = qp[1];
            short8 f;
            f[0] = (short)to_bf16(lo.x); f[1] = (short)to_bf16(lo.y);
            f[2] = (short)to_bf16(lo.z); f[3] = (short)to_bf16(lo.w);
            f[4] = (short)to_bf16(hi.x); f[5] = (short)to_bf16(hi.y);
            f[6] = (short)to_bf16(hi.z); f[7] = (short)to_bf16(hi.w);
            bfrag[bg][kt] = f;
        }
    }

    #pragma unroll 1
    for (int p = 0; p < 2; ++p) {
        int passbase = bid * RPB_ + p * 256; // global row base of this pass
        f32x4 acc[4][2];
        #pragma unroll
        for (int rg = 0; rg < 4; ++rg)
            #pragma unroll
            for (int bg = 0; bg < 2; ++bg)
                acc[rg][bg] = (f32x4){0.f, 0.f, 0.f, 0.f};
        float mmp[4] = {0.f, 0.f, 0.f, 0.f};

        #pragma unroll
        for (int rg = 0; rg < 4; ++rg) {
            int r = passbase + wave * 64 + rg * 16 + l15;
            const float4* mp = (const float4*)(mem + (size_t)((r < N_) ? r : 0) * M_);
            #pragma unroll
            for (int kt = 0; kt < 4; ++kt) {
                float4 lo = mp[kt * 8 + lk * 2];
                float4 hi = mp[kt * 8 + lk * 2 + 1];
                mmp[rg] = fmaf(lo.x, lo.x, fmaf(lo.y, lo.y, fmaf(lo.z, lo.z, fmaf(lo.w, lo.w, mmp[rg]))));
                mmp[rg] = fmaf(hi.x, hi.x, fmaf(hi.y, hi.y, fmaf(hi.z, hi.z, fmaf(hi.w, hi.w, mmp[rg]))));
                short8 af;
                af[0] = (short)to_bf16(lo.x); af[1] = (short)to_bf16(lo.y);
                af[2] = (short)to_bf16(lo.z); af[3] = (short)to_bf16(lo.w);
                af[4] = (short)to_bf16(hi.x); af[5] = (short)to_bf16(hi.y);
                af[6] = (short)to_bf16(hi.z); af[7] = (short)to_bf16(hi.w);
                acc[rg][0] = __builtin_amdgcn_mfma_f32_16x16x32_bf16(af, bfrag[0][kt], acc[rg][0], 0, 0, 0);
                acc[rg][1] = __builtin_amdgcn_mfma_f32_16x16x32_bf16(af, bfrag[1][kt], acc[rg][1], 0, 0, 0);
            }
        }
        // reduce row norms across the 4 k-groups (lanes differing in lk) and stage per-row
        #pragma unroll
        for (int rg = 0; rg < 4; ++rg) {
            float v = mmp[rg] + __shfl_xor(mmp[rg], 16);
            v += __shfl_xor(v, 32);
            if (lane < 16) mm_lds[wave * 64 + rg * 16 + l15] = v;
        }
        __syncthreads();

        // epilogue: score -> ushort key into LDS [batch][row_local]
        #pragma unroll
        for (int rg = 0; rg < 4; ++rg) {
            #pragma unroll
            for (int bg = 0; bg < 2; ++bg) {
                #pragma unroll
                for (int reg = 0; reg < 4; ++reg) {
                    int row_local = wave * 64 + rg * 16 + lk * 4 + reg;
                    int batch = bg * 16 + l15;
                    float dot = acc[rg][bg][reg];
                    float mmv = mm_lds[row_local];
                    float mn = fminf(mmv, MAXN2_);
                    float dsq = fmaxf(qq_s[batch] + mmv - 2.0f * dot, 0.f);
                    float t = dsq / fmaxf(omq_s[batch] * (1.0f - mn), EPS_);
                    key_lds[batch][row_local] = to_bf16(t);
                }
            }
        }
        __syncthreads();

        // transpose-write to global: 64B contiguous per thread, 8 threads per batch
        {
            int batch = tid >> 3, chunk = tid & 7;
            int rbase = passbase + chunk * 32;
            unsigned short* dstp = keyplane + (size_t)batch * NPAD_ + rbase;
            #pragma unroll
            for (int i = 0; i < 4; ++i) {
                int gr = rbase + i * 8;
                uint4 v = *(const uint4*)&key_lds[batch][chunk * 32 + i * 8];
                if (gr + 8 <= N_) {
                    *(uint4*)(dstp + i * 8) = v;
                } else {
                    for (int t = 0; t < 8; ++t)
                        if (gr + t < N_) dstp[i * 8 + t] = key_lds[batch][chunk * 32 + i * 8 + t];
                }
            }
        }
        __syncthreads();
    }
}

// ---------------------------------------------------------------- k4: per-window top-16 (ushort scores)
// 980 blocks = (window, quad); each wave owns 2 batches, 32 keys/lane in regs.
// Key = (score16 << 11) | row_local  (row reconstructed from position).
__global__ __launch_bounds__(256, 4) void k4_sel(const unsigned short* __restrict__ keyplane,
                                                 unsigned* __restrict__ cand_key) {
    int win = blockIdx.x >> 2, quad = blockIdx.x & 3;
    int wave = threadIdx.x >> 6, lane = threadIdx.x & 63;
    int base = win * WIN_;
    #pragma unroll 1
    for (int j = 0; j < 2; ++j) {
        int b = quad * 8 + wave * 2 + j;
        const uint4* kp = (const uint4*)(keyplane + (size_t)b * NPAD_ + base);
        unsigned keys[32];
        #pragma unroll
        for (int i = 0; i < 4; ++i) {
            uint4 v = kp[lane + i * 64]; // 8 ushorts, rows rl0 = (lane+i*64)*8
            int rl0 = (lane + i * 64) * 8;
            int pos = base + rl0;
            unsigned s[8];
            s[0] = v.x & 0xFFFFu; s[1] = v.x >> 16;
            s[2] = v.y & 0xFFFFu; s[3] = v.y >> 16;
            s[4] = v.z & 0xFFFFu; s[5] = v.z >> 16;
            s[6] = v.w & 0xFFFFu; s[7] = v.w >> 16;
            #pragma unroll
            for (int t = 0; t < 8; ++t)
                keys[i * 8 + t] = (pos + t < N_) ? ((s[t] << 11) | (unsigned)(rl0 + t))
                                                 : 0xFFFFFFFFu;
        }
        for (int k = 0; k < KK; ++k) {
            unsigned m = keys[0];
            #pragma unroll
            for (int i = 1; i < 32; ++i) m = min(m, keys[i]);
            #pragma unroll
            for (int off = 32; off >= 1; off >>= 1)
                m = min(m, (unsigned)__shfl_xor((int)m, off));
            if (lane == 0) cand_key[((size_t)win * B_ + b) * KK + k] = m;
            #pragma unroll
            for (int i = 0; i < 32; ++i)
                if (keys[i] == m) keys[i] = 0xFFFFFFFFu;
        }
    }
}

// ---------------------------------------------------------------- k45: merge->32, exact dists, exact top-16, softmax, retrieve, force
__global__ void k45_retrieve(const unsigned* __restrict__ cand_key,
                             const float* __restrict__ mem, const float* __restrict__ query,
                             const float* __restrict__ qstats,
                             const float* __restrict__ Wp, const float* __restrict__ bp,
                             float* __restrict__ force) {
    __shared__ unsigned tv[256 * KK];
    __shared__ int ti[256 * KK];
    __shared__ unsigned mv[64 * KK];
    __shared__ int mi[64 * KK];
    __shared__ int top32_s[KK2];
    __shared__ float q_s[M_];
    __shared__ float d_s[KK2];
    __shared__ float w_s[KK];
    __shared__ int idx_s[KK];
    __shared__ float ret_s[M_];
    int b = blockIdx.x, tid = threadIdx.x; // 256 threads

    // phase 1: per-thread insertion top-16 over all window candidates
    unsigned val[KK]; int idx[KK];
    #pragma unroll
    for (int i = 0; i < KK; ++i) { val[i] = 0xFFFFFFFFu; idx[i] = 0; }
    int nc = NWIN_ * KK; // 3920
    for (int c = tid; c < nc; c += 256) {
        int g = c >> 4, k = c & 15;
        unsigned v = cand_key[((size_t)g * B_ + b) * KK + k];
        int id = g * WIN_ + (int)(v & 2047u);
        if (v < val[KK - 1]) {
            val[KK - 1] = v; idx[KK - 1] = id;
            #pragma unroll
            for (int j = KK - 1; j > 0; --j) {
                if (val[j] < val[j - 1]) {
                    unsigned tvv = val[j]; val[j] = val[j - 1]; val[j - 1] = tvv;
                    int tii = idx[j]; idx[j] = idx[j - 1]; idx[j - 1] = tii;
                }
            }
        }
    }
    if (tid < M_) q_s[tid] = query[b * M_ + tid];
    #pragma unroll
    for (int i = 0; i < KK; ++i) { tv[tid * KK + i] = val[i]; ti[tid * KK + i] = idx[i]; }
    __syncthreads();

    // phase 2: tree-merge to approx top-32 on wave 0
    if (tid < 64) {
        #pragma unroll
        for (int i = 0; i < KK; ++i) { val[i] = 0xFFFFFFFFu; idx[i] = 0; }
        for (int t = tid * 4; t < tid * 4 + 4; ++t) {
            for (int i = 0; i < KK; ++i) {
                unsigned v = tv[t * KK + i]; int id = ti[t * KK + i];
                if (v >= val[KK - 1]) break;
                val[KK - 1] = v; idx[KK - 1] = id;
                #pragma unroll
                for (int j = KK - 1; j > 0; --j) {
                    if (val[j] < val[j - 1]) {
                        unsigned tvv = val[j]; val[j] = val[j - 1]; val[j - 1] = tvv;
                        int tii = idx[j]; idx[j] = idx[j - 1]; idx[j - 1] = tii;
                    }
                }
            }
        }
        #pragma unroll
        for (int i = 0; i < KK; ++i) { mv[tid * KK + i] = val[i]; mi[tid * KK + i] = idx[i]; }
        int h = 0;
        for (int k = 0; k < KK2; ++k) {
            unsigned cv = (h < KK) ? mv[tid * KK + h] : 0xFFFFFFFFu;
            int ci = (h < KK) ? mi[tid * KK + h] : 0;
            unsigned bestv = cv; int bestl = tid;
            #pragma unroll
            for (int off = 32; off >= 1; off >>= 1) {
                unsigned ov = (unsigned)__shfl_down((int)bestv, off);
                int ol = __shfl_down(bestl, off);
                if (ov < bestv) { bestv = ov; bestl = ol; }
            }
            bestl = __shfl(bestl, 0);
            if (tid == bestl) {
                top32_s[k] = (ci < 0) ? 0 : ((ci >= N_) ? (N_ - 1) : ci);
                h++;
            }
        }
    }
    __syncthreads();

    // phase 3: exact distances on the 32 finalists
    float qq = qstats[b * 2], omq = qstats[b * 2 + 1];
    int wave = tid >> 6, lane = tid & 63;
    for (int ii = wave; ii < KK2; ii += 4) {
        const float* mr = mem + (size_t)top32_s[ii] * M_;
        float a0 = mr[lane], a1 = mr[lane + 64];
        float p = q_s[lane] * a0 + q_s[lane + 64] * a1;
        float mm = a0 * a0 + a1 * a1;
        #pragma unroll
        for (int off = 32; off >= 1; off >>= 1) {
            p += __shfl_down(p, off);
            mm += __shfl_down(mm, off);
        }
        if (lane == 0) {
            float dsq = fmaxf(qq + mm - 2.0f * p, 0.f);
            float mn = fminf(mm, MAXN2_);
            float t = dsq / fmaxf(omq * (1.0f - mn), EPS_);
            d_s[ii] = acoshf(1.0f + 2.0f * t);
        }
    }
    __syncthreads();
    // exact top-16 of the 32 (tie-break by memory index), then softmax
    if (tid == 0) {
        bool used[KK2];
        for (int i = 0; i < KK2; ++i) used[i] = false;
        float seld[KK];
        for (int k = 0; k < KK; ++k) {
            float bd = FLT_MAX; int bi = -1;
            for (int i = 0; i < KK2; ++i) {
                if (used[i]) continue;
                if (d_s[i] < bd || (d_s[i] == bd && (bi < 0 || top32_s[i] < top32_s[bi]))) {
                    bd = d_s[i]; bi = i;
                }
            }
            used[bi] = true; seld[k] = bd; idx_s[k] = top32_s[bi];
        }
        float dmin = seld[0];
        for (int i = 1; i < KK; ++i) dmin = fminf(dmin, seld[i]);
        float Z = 0.f;
        for (int i = 0; i < KK; ++i) {
            float w = expf((dmin - seld[i]) * (1.0f / TAU_));
            w_s[i] = w; Z += w;
        }
        float iZ = 1.0f / Z;
        for (int i = 0; i < KK; ++i) w_s[i] *= iZ;
    }
    __syncthreads();
    // phase 4: weighted retrieve + project to H
    if (tid < M_) {
        float r = 0.f;
        for (int i = 0; i < KK; ++i) r = fmaf(w_s[i], mem[(size_t)idx_s[i] * M_ + tid], r);
        ret_s[tid] = r;
    }
    __syncthreads();
    #pragma unroll
    for (int j = 0; j < 4; ++j) {
        int h = tid + j * 256;
        float f = bp[h];
        for (int k = 0; k < M_; ++k) f = fmaf(ret_s[k], Wp[k * H_ + h], f);
        force[b * H_ + h] = f;
    }
}

// ---------------------------------------------------------------- k6: out = hidden + alpha*force
__global__ __launch_bounds__(256) void k6_out(const float* __restrict__ hid,
                                              const float* __restrict__ force,
                                              float* __restrict__ out) {
    const float4* h4 = (const float4*)hid;
    const float4* f4 = (const float4*)force;
    float4* o4 = (float4*)out;
    int n4 = B_ * S_ * H_ / 4; // 16,777,216
    for (int i = blockIdx.x * blockDim.x + threadIdx.x; i < n4; i += gridDim.x * blockDim.x) {
        int b = i >> 19; // (S*H/4) = 2^19
        float4 hv = h4[i];
        float4 fv = f4[(b << 8) + (i & 255)];
        float4 ov;
        ov.x = fmaf(ALPHA_, fv.x, hv.x);
        ov.y = fmaf(ALPHA_, fv.y, hv.y);
        ov.z = fmaf(ALPHA_, fv.z, hv.z);
        ov.w = fmaf(ALPHA_, fv.w, hv.w);
        o4[i] = ov;
    }
}

// ---------------------------------------------------------------- launch
extern "C" void kernel_launch(void* const* d_in, const int* in_sizes, int n_in,
                              void* d_out, int out_size, void* d_ws, size_t ws_size,
                              hipStream_t stream) {
    const float* hid    = (const float*)d_in[0];
    const float* W1     = (const float*)d_in[1];
    const float* b1     = (const float*)d_in[2];
    const float* ln_g   = (const float*)d_in[3];
    const float* ln_b   = (const float*)d_in[4];
    const float* W2     = (const float*)d_in[5];
    const float* b2     = (const float*)d_in[6];
    const float* qorig  = (const float*)d_in[7];
    const float* mem    = (const float*)d_in[8];
    const float* Wp     = (const float*)d_in[9];
    const float* bp     = (const float*)d_in[10];
    float* out = (float*)d_out;

    char* ws = (char*)d_ws;
    size_t off = 0;
    float* pp = (float*)(ws + off);        off += (size_t)B_ * SC_ * H_ * 4;   // 8 MB
    float* query = (float*)(ws + off);     off += (size_t)B_ * M_ * 4;
    float* qstats = (float*)(ws + off);    off += (size_t)B_ * 2 * 4;
    off = (off + 255) & ~(size_t)255;
    unsigned short* keyplane = (unsigned short*)(ws + off); off += (size_t)B_ * NPAD_ * 2; // 32.1 MB
    off = (off + 255) & ~(size_t)255;
    unsigned* cand_key = (unsigned*)(ws + off); off += (size_t)NWIN_ * B_ * KK * 4;
    float* force = (float*)(ws + off);     off += (size_t)B_ * H_ * 4;
    (void)ws_size; (void)in_sizes; (void)n_in; (void)out_size;

    hipLaunchKernelGGL(k1_pool, dim3(B_ * SC_), dim3(256), 0, stream, hid, pp);
    hipLaunchKernelGGL(k2_query, dim3(B_), dim3(128), 0, stream, pp, W1, b1, ln_g, ln_b,
                       W2, b2, qorig, query, qstats);
    hipLaunchKernelGGL(k3_scores, dim3(NBLK_), dim3(256), 0, stream, mem, query, qstats, keyplane);
    hipLaunchKernelGGL(k4_sel, dim3(NWIN_ * 4), dim3(256), 0, stream, keyplane, cand_key);
    hipLaunchKernelGGL(k45_retrieve, dim3(B_), dim3(256), 0, stream, cand_key,
                       mem, query, qstats, Wp, bp, force);
    hipLaunchKernelGGL(k6_out, dim3(2048), dim3(256), 0, stream, hid, force, out);
}